// Round 3
// baseline (712.124 us; speedup 1.0000x reference)
//
#include <hip/hip_runtime.h>

#define DD 128      // GNN_DIM == NODE_FEAT
#define HDIM 512    // H * D
#define EFEAT 32
#define NHEAD 4

typedef short s16x8 __attribute__((ext_vector_type(8)));
typedef float f32x4 __attribute__((ext_vector_type(4)));

__device__ __forceinline__ float lrelu(float x){ return x > 0.f ? x : 0.2f*x; }

__device__ __forceinline__ unsigned short f2bf(float f){
  unsigned u = __float_as_uint(f);
  unsigned r = (u + 0x7FFFu + ((u >> 16) & 1u)) >> 16;
  return (unsigned short)r;
}
__device__ __forceinline__ float bf2f(unsigned short u){
  return __uint_as_float(((unsigned)u) << 16);
}

__device__ __forceinline__ float waveReduceSum(float v){
  #pragma unroll
  for (int m = 1; m < 64; m <<= 1) v += __shfl_xor(v, m, 64);
  return v;
}
__device__ __forceinline__ float quadReduceSum(float v){
  v += __shfl_xor(v, 1, 64); v += __shfl_xor(v, 2, 64);
  v += __shfl_xor(v, 4, 64); v += __shfl_xor(v, 8, 64);
  return v;
}

// ---------------- edge-attr column sums (float4, saturating grid) ----------------
__global__ __launch_bounds__(256) void ea_sum4_kernel(const float* __restrict__ ea,
                                                      float* __restrict__ ea_sum, int E){
  __shared__ float s[EFEAT];
  int t = threadIdx.x;
  if (t < EFEAT) s[t] = 0.f;
  __syncthreads();
  int nvec = E*8;
  float4 acc = make_float4(0.f, 0.f, 0.f, 0.f);
  for (int i = blockIdx.x*256 + t; i < nvec; i += gridDim.x*256){
    float4 v = *((const float4*)ea + i);
    acc.x += v.x; acc.y += v.y; acc.z += v.z; acc.w += v.w;
  }
  int cg = (t & 7)*4;
  atomicAdd(&s[cg + 0], acc.x); atomicAdd(&s[cg + 1], acc.y);
  atomicAdd(&s[cg + 2], acc.z); atomicAdd(&s[cg + 3], acc.w);
  __syncthreads();
  if (t < EFEAT) atomicAdd(&ea_sum[t], s[t]);
}

// ---------------- CSR build over dst ----------------
__global__ void hist_kernel(const int* __restrict__ dst, int* __restrict__ deg, int E){
  int e = blockIdx.x*blockDim.x + threadIdx.x;
  if (e < E) atomicAdd(&deg[dst[e]], 1);
}

__global__ void scan_kernel(const int* __restrict__ deg, int* __restrict__ offs, int N){
  __shared__ int s[1024];
  int t = threadIdx.x;
  int chunk = (N + 1023) >> 10;
  int b = t*chunk, e = min(b + chunk, N);
  int sum = 0;
  for (int i = b; i < e; i++) sum += deg[i];
  s[t] = sum;
  __syncthreads();
  for (int d = 1; d < 1024; d <<= 1){
    int x = (t >= d) ? s[t - d] : 0;
    __syncthreads();
    s[t] += x;
    __syncthreads();
  }
  int run = s[t] - sum;
  for (int i = b; i < e; i++){ offs[i] = run; run += deg[i]; }
  if (t == 1023) offs[N] = s[1023];
}

__global__ void scatter_kernel(const int* __restrict__ dst, const int* __restrict__ src,
                               int* __restrict__ cursor, int* __restrict__ csrc,
                               int* __restrict__ posOf, int E){
  int e = blockIdx.x*blockDim.x + threadIdx.x;
  if (e < E){
    int d = dst[e];
    int p = atomicAdd(&cursor[d], 1);
    csrc[p] = src[e];
    posOf[e] = p;
  }
}

// ---------------- convert edge attrs, scatter into CSR order (bf16) ------------
__global__ void eap_prep_kernel(const float* __restrict__ ea, const int* __restrict__ posOf,
                                unsigned short* __restrict__ eap, int E){
  int idx = blockIdx.x*blockDim.x + threadIdx.x;
  int e = idx >> 3, q = idx & 7;
  if (e >= E) return;
  int p = posOf[e];
  float4 v = *((const float4*)(ea + (size_t)e*EFEAT) + q);
  ushort4 u = make_ushort4(f2bf(v.x), f2bf(v.y), f2bf(v.z), f2bf(v.w));
  *((ushort4*)(eap + (size_t)p*EFEAT) + q) = u;
}

// ---------------- per-edge attention logits for ALL layers (CSR order) ---------
__global__ __launch_bounds__(256) void ale_prep_kernel(
    const unsigned short* __restrict__ eap, const float* __restrict__ we_att,
    float* __restrict__ ale, int E, int L){
  __shared__ float sea[256][33];
  __shared__ float swe[6*EFEAT*NHEAD];
  int t = threadIdx.x;
  for (int i = t; i < L*EFEAT*NHEAD; i += 256) swe[i] = we_att[i];
  size_t p0 = (size_t)blockIdx.x*256;
  int navail = min(256, E - (int)p0);
  for (int i = t; i < navail*4; i += 256){
    uint4 v = *((const uint4*)(eap + p0*EFEAT) + i);
    int el = i >> 2, q = i & 3;
    unsigned arr[4] = {v.x, v.y, v.z, v.w};
    #pragma unroll
    for (int j = 0; j < 4; j++){
      sea[el][q*8 + j*2]     = bf2f((unsigned short)(arr[j] & 0xffff));
      sea[el][q*8 + j*2 + 1] = bf2f((unsigned short)(arr[j] >> 16));
    }
  }
  __syncthreads();
  if ((int)p0 + t >= E) return;
  float ea[EFEAT];
  #pragma unroll
  for (int f = 0; f < EFEAT; f++) ea[f] = sea[t][f];
  size_t p = p0 + t;
  for (int l = 0; l < L; l++){
    float a0 = 0.f, a1 = 0.f, a2 = 0.f, a3 = 0.f;
    const float* w = &swe[l*EFEAT*NHEAD];
    #pragma unroll
    for (int f = 0; f < EFEAT; f++){
      float v = ea[f];
      a0 += v*w[f*4 + 0]; a1 += v*w[f*4 + 1];
      a2 += v*w[f*4 + 2]; a3 += v*w[f*4 + 3];
    }
    *(float4*)&ale[((size_t)l*E + p)*4] = make_float4(a0, a1, a2, a3);
  }
}

// ---------------- fp32 -> bf16 convert (float4 -> ushort4) ----------------
__global__ void bf16_conv_kernel(const float* __restrict__ in,
                                 unsigned short* __restrict__ out, int nvec){
  int i = blockIdx.x*blockDim.x + threadIdx.x;
  if (i >= nvec) return;
  float4 v = *((const float4*)in + i);
  *((ushort4*)out + i) = make_ushort4(f2bf(v.x), f2bf(v.y), f2bf(v.z), f2bf(v.w));
}

// ---------------- parallel folds: wave per output ----------------
__global__ __launch_bounds__(256) void fold_ws_kernel(const float* __restrict__ gat_W,
    const float* __restrict__ att_src, const float* __restrict__ att_dst,
    float* __restrict__ ws_att, int L){
  int wave = threadIdx.x >> 6, lane = threadIdx.x & 63;
  int idx = blockIdx.x*4 + wave;
  if (idx >= L*DD*8) return;
  int j = idx & 7; int k = (idx >> 3) & 127; int l = idx >> 10;
  int h = j & 3;
  const float* att = (j < 4) ? att_src : att_dst;
  const float* av = att + (size_t)(l*NHEAD + h)*DD;
  const float* Wl = gat_W + (size_t)l*DD*HDIM + (size_t)k*HDIM + h*DD;
  float acc = Wl[lane]*av[lane] + Wl[lane + 64]*av[lane + 64];
  acc = waveReduceSum(acc);
  if (lane == 0) ws_att[idx] = acc;
}

__global__ __launch_bounds__(256) void fold_we_kernel(const float* __restrict__ gat_We,
    const float* __restrict__ att_edge, float* __restrict__ we_att, int L){
  int wave = threadIdx.x >> 6, lane = threadIdx.x & 63;
  int idx = blockIdx.x*4 + wave;
  if (idx >= L*EFEAT*NHEAD) return;
  int h = idx & 3; int f = (idx >> 2) & 31; int l = idx >> 7;
  const float* av = att_edge + (size_t)(l*NHEAD + h)*DD;
  const float* Wel = gat_We + (size_t)l*EFEAT*HDIM + (size_t)f*HDIM + h*DD;
  float acc = Wel[lane]*av[lane] + Wel[lane + 64]*av[lane + 64];
  acc = waveReduceSum(acc);
  if (lane == 0) we_att[idx] = acc;
}

__global__ void fold_self_kernel(const float* __restrict__ we_att,
    const float* __restrict__ ea_sum, float invE, float* __restrict__ al_self, int L){
  int t = threadIdx.x;
  if (t >= L*NHEAD) return;
  int h = t & 3; int l = t >> 2;
  float acc = 0.f;
  for (int f = 0; f < EFEAT; f++) acc += ea_sum[f]*invE * we_att[(l*EFEAT + f)*NHEAD + h];
  al_self[t] = acc;
}

// ---------------- gat_W -> bf16 Bt[l][d][h*128+k], LDS-tiled transpose ----------------
__global__ __launch_bounds__(256) void bt_prep_kernel(const float* __restrict__ gat_W,
                                                      unsigned short* __restrict__ Bt, int LH){
  __shared__ float tile[32][33];
  int blk = blockIdx.x;
  int lh = blk >> 4;
  if (lh >= LH) return;
  int tl = blk & 15;
  int k0 = (tl & 3)*32, d0 = (tl >> 2)*32;
  int l = lh >> 2, h = lh & 3;
  const float* in = gat_W + (size_t)l*DD*HDIM + h*DD;
  unsigned short* outp = Bt + (size_t)l*DD*HDIM + h*DD;
  int tx = threadIdx.x & 31, ty = threadIdx.x >> 5;
  #pragma unroll
  for (int i = 0; i < 4; i++){
    int k = k0 + ty + i*8;
    tile[ty + i*8][tx] = in[(size_t)k*HDIM + d0 + tx];
  }
  __syncthreads();
  #pragma unroll
  for (int i = 0; i < 4; i++){
    int d = d0 + ty + i*8;
    outp[(size_t)d*HDIM + k0 + tx] = f2bf(tile[tx][ty + i*8]);
  }
}

// ---------------- embW -> bf16 transposed [128][128] ----------------
__global__ void embwt_prep_kernel(const float* __restrict__ embW,
                                  unsigned short* __restrict__ Wt){
  int i = blockIdx.x*blockDim.x + threadIdx.x;
  if (i >= DD*DD) return;
  int n = i >> 7, k = i & 127;
  Wt[i] = f2bf(embW[(size_t)k*DD + n]);
}

// ---------------- [W1a | W1b] -> bf16 transposed [256][128] ----------------
__global__ void w1ab_prep_kernel(const float* __restrict__ hW1,
                                 unsigned short* __restrict__ Bhd){
  int i = blockIdx.x*blockDim.x + threadIdx.x;
  if (i >= 256*DD) return;
  int n = i >> 7, k = i & 127;
  float v = (n < 128) ? hW1[(size_t)k*DD + n] : hW1[(size_t)(128 + k)*DD + (n - 128)];
  Bhd[i] = f2bf(v);
}

// ---------------- W1c -> MFMA B-fragment layout: Bh[c][lane][j] ----------------
__global__ void w1c_prep_kernel(const float* __restrict__ W1c, unsigned short* __restrict__ Bh){
  int i = blockIdx.x*blockDim.x + threadIdx.x;
  if (i >= 8*64*8) return;
  int j = i & 7, lane = (i >> 3) & 63, c = i >> 9;
  int ln15 = lane & 15, quad = lane >> 4;
  int k = quad*8 + j, n = c*16 + ln15;
  Bh[i] = f2bf(W1c[(size_t)k*DD + n]);
}

// ---------------- unified MFMA GEMM + fused epilogues ----------------
// KD==512: K-split-4. Block = 16 rows; each wave computes one K=128 chunk with
// B fragments loaded directly from global (Bt is L2-resident), partial sums
// reduced via LDS, wave 0 runs the epilogue. Grid = N/16 -> 4x the waves of the
// old 64-row-block structure (fixes the 15%-occupancy latency bound).
// KD==128: original single-chunk LDS-staged path (4 row-waves, 64 rows/block).
template<int KD, int NOUT>
__global__ __launch_bounds__(256, 4) void gemm_fused_kernel(
    const unsigned short* __restrict__ A, const unsigned short* __restrict__ Bt,
    const float* __restrict__ bias, float scale, int relu, int mode,
    const float* __restrict__ ln_scale, const float* __restrict__ ln_bias,
    const float* __restrict__ gamma, const float* __restrict__ beta,
    const float* __restrict__ ws_att,
    unsigned short* __restrict__ hm_bf, float* __restrict__ al_s,
    float* __restrict__ al_d, unsigned short* __restrict__ outbf, int N){
  constexpr int NC = NOUT/16;
  __shared__ float s_att[8*DD];
  __shared__ float sP[4][DD];
  int t = threadIdx.x;
  if (mode == 0){
    for (int i = t; i < DD*8; i += 256){
      int col = i & 127, j = i >> 7;
      s_att[j*DD + col] = ws_att[col*8 + j];
    }
    for (int i = t; i < DD; i += 256){
      sP[0][i] = ln_scale[i]; sP[1][i] = ln_bias[i];
      sP[2][i] = gamma[i];    sP[3][i] = beta[i];
    }
  }
  int wave = t >> 6, lane = t & 63;
  int ln15 = lane & 15, quad = lane >> 4;

  f32x4 acc[NC];
  #pragma unroll
  for (int c = 0; c < NC; c++) acc[c] = (f32x4)(0.f);

  int row0;
  bool epi = true;

  if constexpr (KD == 512){
    __shared__ float sacc[3][NC][64][4];
    row0 = blockIdx.x*16;
    int arow = row0 + ln15;
    if (arow > N - 1) arow = N - 1;
    const unsigned short* aptr = A + (size_t)arow*KD + wave*128 + quad*8;
    const unsigned short* bptr = Bt + (size_t)ln15*KD + wave*128 + quad*8;
    s16x8 af[4];
    #pragma unroll
    for (int ks = 0; ks < 4; ks++) af[ks] = *(const s16x8*)(aptr + ks*32);
    #pragma unroll
    for (int ks = 0; ks < 4; ks++){
      s16x8 b[NC];
      #pragma unroll
      for (int c = 0; c < NC; c++)
        b[c] = *(const s16x8*)(bptr + (size_t)(c*16)*KD + ks*32);
      #pragma unroll
      for (int c = 0; c < NC; c++)
        acc[c] = __builtin_amdgcn_mfma_f32_16x16x32_bf16(af[ks], b[c], acc[c], 0, 0, 0);
    }
    if (wave != 0){
      #pragma unroll
      for (int c = 0; c < NC; c++)
        *(f32x4*)&sacc[wave - 1][c][lane][0] = acc[c];
    }
    __syncthreads();
    if (wave != 0){
      epi = false;
    } else {
      #pragma unroll
      for (int c = 0; c < NC; c++){
        #pragma unroll
        for (int j = 0; j < 3; j++)
          acc[c] += *(const f32x4*)&sacc[j][c][lane][0];
      }
    }
  } else {
    constexpr int GRP = (NC > 8) ? 8 : NC;
    __shared__ unsigned short Bs[NC*2048];
    row0 = blockIdx.x*64 + wave*16;
    int arow = row0 + ln15;
    if (arow > N - 1) arow = N - 1;
    const unsigned short* aptr = A + (size_t)arow*KD;
    // stage B (two-phase: batch loads -> regs -> ds_writes)
    #pragma unroll
    for (int g0 = 0; g0 < NC/GRP; g0++){
      uint4 tmp[GRP];
      #pragma unroll
      for (int i = 0; i < GRP; i++){
        int g = (g0*GRP + i)*256 + t;
        int gl = g & 63;
        int gidx = g >> 6;
        int gc = gidx % NC, gks = gidx / NC;
        tmp[i] = *(const uint4*)(Bt + (size_t)(gc*16 + (gl & 15))*KD
                                 + gks*32 + (gl >> 4)*8);
      }
      #pragma unroll
      for (int i = 0; i < GRP; i++){
        int g = (g0*GRP + i)*256 + t;
        *(uint4*)&Bs[(size_t)g*8] = tmp[i];
      }
    }
    s16x8 af[4];
    #pragma unroll
    for (int ks = 0; ks < 4; ks++)
      af[ks] = *(const s16x8*)(aptr + ks*32 + quad*8);
    __syncthreads();
    #pragma unroll
    for (int ks = 0; ks < 4; ks++){
      #pragma unroll
      for (int c = 0; c < NC; c++){
        s16x8 b = *(const s16x8*)&Bs[(size_t)((ks*NC + c)*64 + lane)*8];
        acc[c] = __builtin_amdgcn_mfma_f32_16x16x32_bf16(af[ks], b, acc[c], 0, 0, 0);
      }
    }
  }

  if (!epi) return;

  float bv[NC];
  #pragma unroll
  for (int c = 0; c < NC; c++){
    if constexpr (NOUT == 256) bv[c] = (c < 8) ? bias[c*16 + ln15] : 0.f;
    else bv[c] = bias[c*16 + ln15];
  }

  #pragma unroll
  for (int r = 0; r < 4; r++){
    int row = row0 + quad*4 + r;
    bool valid = (row < N);
    float hv[NC];
    #pragma unroll
    for (int c = 0; c < NC; c++){
      float v = scale*acc[c][r] + bv[c];
      hv[c] = relu ? fmaxf(v, 0.f) : v;
    }
    if (mode == 1){
      if (valid){
        if constexpr (NOUT == 256){
          // head layout: pbuf[row][ln15*8 + c] (first 128) / [128 + ln15*8 + c-8]
          unsigned short us[16];
          #pragma unroll
          for (int c = 0; c < 16; c++) us[c] = f2bf(hv[c]);
          uint4 va, vb;
          va.x = (unsigned)us[0] | ((unsigned)us[1] << 16);
          va.y = (unsigned)us[2] | ((unsigned)us[3] << 16);
          va.z = (unsigned)us[4] | ((unsigned)us[5] << 16);
          va.w = (unsigned)us[6] | ((unsigned)us[7] << 16);
          vb.x = (unsigned)us[8] | ((unsigned)us[9] << 16);
          vb.y = (unsigned)us[10] | ((unsigned)us[11] << 16);
          vb.z = (unsigned)us[12] | ((unsigned)us[13] << 16);
          vb.w = (unsigned)us[14] | ((unsigned)us[15] << 16);
          *(uint4*)(outbf + (size_t)row*256 + ln15*8) = va;
          *(uint4*)(outbf + (size_t)row*256 + 128 + ln15*8) = vb;
        } else {
          #pragma unroll
          for (int c = 0; c < NC; c++)
            outbf[(size_t)row*NOUT + c*16 + ln15] = f2bf(hv[c]);
        }
      }
      continue;
    }
    if constexpr (NOUT == 128){
      float sum = 0.f;
      #pragma unroll
      for (int c = 0; c < NC; c++) sum += hv[c];
      sum = quadReduceSum(sum);
      float mu = sum * (1.f/128.f);
      float vs = 0.f;
      #pragma unroll
      for (int c = 0; c < NC; c++){ float d = hv[c] - mu; vs += d*d; }
      vs = quadReduceSum(vs);
      float rstd = rsqrtf(vs*(1.f/128.f) + 1e-5f);
      float m[NC];
      #pragma unroll
      for (int c = 0; c < NC; c++){
        int col = c*16 + ln15;
        float hn = (hv[c] - mu)*rstd*sP[0][col] + sP[1][col];
        m[c] = sP[2][col]*hn + sP[3][col];
        if (valid) hm_bf[(size_t)row*DD + col] = f2bf(m[c]);
      }
      float alv[8];
      #pragma unroll
      for (int j = 0; j < 8; j++){
        float a = 0.f;
        #pragma unroll
        for (int c = 0; c < NC; c++) a += m[c]*s_att[j*DD + c*16 + ln15];
        alv[j] = quadReduceSum(a);
      }
      if (ln15 == 0 && valid){
        *(float4*)&al_s[(size_t)row*4] = make_float4(alv[0], alv[1], alv[2], alv[3]);
        *(float4*)&al_d[(size_t)row*4] = make_float4(alv[4], alv[5], alv[6], alv[7]);
      }
    }
  }
}

// ---------------- fused softmax + weighted aggregation (block per node) --------
__global__ __launch_bounds__(64) void aggregate4_kernel(
    const unsigned short* __restrict__ hm_bf, const float* __restrict__ ale,
    const float* __restrict__ al_s, const float* __restrict__ al_d,
    const float* __restrict__ al_self4, const int* __restrict__ offs,
    const int* __restrict__ csrc, unsigned short* __restrict__ z, int N){
  __shared__ float sw0[64], sw1[64], sw2[64], sw3[64];
  __shared__ int ssrc[64];
  int n = blockIdx.x, t = threadIdx.x;
  int beg = offs[n], end = offs[n + 1];
  float4 aslf = *(const float4*)al_self4;
  float4 asn = *(const float4*)&al_s[(size_t)n*4];
  float4 adn = *(const float4*)&al_d[(size_t)n*4];
  float e0 = __expf(lrelu(asn.x + adn.x + aslf.x));
  float e1 = __expf(lrelu(asn.y + adn.y + aslf.y));
  float e2 = __expf(lrelu(asn.z + adn.z + aslf.z));
  float e3 = __expf(lrelu(asn.w + adn.w + aslf.w));
  ushort2 hv = *((const ushort2*)(hm_bf + (size_t)n*DD) + t);
  float h0 = bf2f(hv.x), h1 = bf2f(hv.y);
  float ac00 = e0*h0, ac01 = e0*h1;
  float ac10 = e1*h0, ac11 = e1*h1;
  float ac20 = e2*h0, ac21 = e2*h1;
  float ac30 = e3*h0, ac31 = e3*h1;
  float den0 = e0, den1 = e1, den2 = e2, den3 = e3;
  for (int c0 = beg; c0 < end; c0 += 64){
    int p = c0 + t;
    if (p < end){
      int s = csrc[p];
      float4 ae = *(const float4*)&ale[(size_t)p*4];
      float4 as = *(const float4*)&al_s[(size_t)s*4];
      sw0[t] = __expf(lrelu(as.x + adn.x + ae.x));
      sw1[t] = __expf(lrelu(as.y + adn.y + ae.y));
      sw2[t] = __expf(lrelu(as.z + adn.z + ae.z));
      sw3[t] = __expf(lrelu(as.w + adn.w + ae.w));
      ssrc[t] = s;
    }
    __syncthreads();
    int cnt = min(64, end - c0);
    int i = 0;
    for (; i + 4 <= cnt; i += 4){   // 4-deep: keep 4 scattered row-loads in flight
      int sA = ssrc[i], sB = ssrc[i + 1], sC = ssrc[i + 2], sD = ssrc[i + 3];
      ushort2 vA = *((const ushort2*)(hm_bf + (size_t)sA*DD) + t);
      ushort2 vB = *((const ushort2*)(hm_bf + (size_t)sB*DD) + t);
      ushort2 vC = *((const ushort2*)(hm_bf + (size_t)sC*DD) + t);
      ushort2 vD = *((const ushort2*)(hm_bf + (size_t)sD*DD) + t);
      float wA0 = sw0[i], wA1 = sw1[i], wA2 = sw2[i], wA3 = sw3[i];
      float wB0 = sw0[i+1], wB1 = sw1[i+1], wB2 = sw2[i+1], wB3 = sw3[i+1];
      float wC0 = sw0[i+2], wC1 = sw1[i+2], wC2 = sw2[i+2], wC3 = sw3[i+2];
      float wD0 = sw0[i+3], wD1 = sw1[i+3], wD2 = sw2[i+3], wD3 = sw3[i+3];
      float vA0 = bf2f(vA.x), vA1 = bf2f(vA.y);
      float vB0 = bf2f(vB.x), vB1 = bf2f(vB.y);
      float vC0 = bf2f(vC.x), vC1 = bf2f(vC.y);
      float vD0 = bf2f(vD.x), vD1 = bf2f(vD.y);
      ac00 += wA0*vA0 + wB0*vB0 + wC0*vC0 + wD0*vD0;
      ac01 += wA0*vA1 + wB0*vB1 + wC0*vC1 + wD0*vD1;
      ac10 += wA1*vA0 + wB1*vB0 + wC1*vC0 + wD1*vD0;
      ac11 += wA1*vA1 + wB1*vB1 + wC1*vC1 + wD1*vD1;
      ac20 += wA2*vA0 + wB2*vB0 + wC2*vC0 + wD2*vD0;
      ac21 += wA2*vA1 + wB2*vB1 + wC2*vC1 + wD2*vD1;
      ac30 += wA3*vA0 + wB3*vB0 + wC3*vC0 + wD3*vD0;
      ac31 += wA3*vA1 + wB3*vB1 + wC3*vC1 + wD3*vD1;
      den0 += wA0 + wB0 + wC0 + wD0; den1 += wA1 + wB1 + wC1 + wD1;
      den2 += wA2 + wB2 + wC2 + wD2; den3 += wA3 + wB3 + wC3 + wD3;
    }
    for (; i < cnt; i++){
      int s = ssrc[i];
      float w0 = sw0[i], w1 = sw1[i], w2 = sw2[i], w3 = sw3[i];
      ushort2 v2 = *((const ushort2*)(hm_bf + (size_t)s*DD) + t);
      float v0 = bf2f(v2.x), v1 = bf2f(v2.y);
      ac00 += w0*v0; ac01 += w0*v1;
      ac10 += w1*v0; ac11 += w1*v1;
      ac20 += w2*v0; ac21 += w2*v1;
      ac30 += w3*v0; ac31 += w3*v1;
      den0 += w0; den1 += w1; den2 += w2; den3 += w3;
    }
    __syncthreads();
  }
  float r0 = 1.f/(den0 + 1e-16f), r1 = 1.f/(den1 + 1e-16f);
  float r2 = 1.f/(den2 + 1e-16f), r3 = 1.f/(den3 + 1e-16f);
  size_t zb = (size_t)n*HDIM;
  ushort2* zp = (ushort2*)(z + zb);
  zp[0*64 + t] = make_ushort2(f2bf(ac00*r0), f2bf(ac01*r0));
  zp[1*64 + t] = make_ushort2(f2bf(ac10*r1), f2bf(ac11*r1));
  zp[2*64 + t] = make_ushort2(f2bf(ac20*r2), f2bf(ac21*r2));
  zp[3*64 + t] = make_ushort2(f2bf(ac30*r3), f2bf(ac31*r3));
}

// ---------------- MFMA edge head: out[e] = relu(p[s]+p[d]+ea@W1c)@W2 + b2 ------------
__global__ __launch_bounds__(256) void head_mfma_kernel(
    const unsigned short* __restrict__ eap, const int* __restrict__ posOf,
    const unsigned short* __restrict__ Bh, const unsigned short* __restrict__ pbuf,
    const float* __restrict__ W2, const float* __restrict__ b2,
    const int* __restrict__ srcA, const int* __restrict__ dstA,
    float* __restrict__ out, int E){
  int t = threadIdx.x;
  int wave = t >> 6, lane = t & 63;
  int ln15 = lane & 15, quad = lane >> 4;
  int e0 = (blockIdx.x*4 + wave)*16;
  if (e0 >= E) return;
  int arow = e0 + ln15;
  if (arow > E - 1) arow = E - 1;
  int ap = posOf[arow];
  s16x8 a = *(const s16x8*)(eap + (size_t)ap*EFEAT + quad*8);
  f32x4 acc[8];
  #pragma unroll
  for (int c = 0; c < 8; c++){
    s16x8 b = *(const s16x8*)(Bh + ((size_t)c*64 + lane)*8);
    acc[c] = __builtin_amdgcn_mfma_f32_16x16x32_bf16(a, b, (f32x4)(0.f), 0, 0, 0);
  }
  float w2v[8];
  #pragma unroll
  for (int c = 0; c < 8; c++) w2v[c] = W2[c*16 + ln15];
  float res[4];
  #pragma unroll
  for (int r = 0; r < 4; r++){
    int e = e0 + quad*4 + r;
    int ec = (e < E) ? e : E - 1;
    int s = srcA[ec], d = dstA[ec];
    s16x8 pa = *(const s16x8*)(pbuf + (size_t)s*256 + ln15*8);
    s16x8 pb = *(const s16x8*)(pbuf + (size_t)d*256 + 128 + ln15*8);
    float sum = 0.f;
    #pragma unroll
    for (int c = 0; c < 8; c++){
      float q = acc[c][r] + bf2f((unsigned short)pa[c]) + bf2f((unsigned short)pb[c]);
      sum += fmaxf(q, 0.f) * w2v[c];
    }
    res[r] = sum;
  }
  #pragma unroll
  for (int r = 0; r < 4; r++){
    float v = res[r];
    v += __shfl_xor(v, 1, 64); v += __shfl_xor(v, 2, 64);
    v += __shfl_xor(v, 4, 64); v += __shfl_xor(v, 8, 64);
    res[r] = v;
  }
  if (ln15 == 0){
    float bb = b2[0];
    #pragma unroll
    for (int r = 0; r < 4; r++){
      int e = e0 + quad*4 + r;
      if (e < E) out[e] = res[r] + bb;
    }
  }
}

extern "C" void kernel_launch(void* const* d_in, const int* in_sizes, int n_in,
                              void* d_out, int out_size, void* d_ws, size_t ws_size,
                              hipStream_t stream){
  const float* x      = (const float*)d_in[0];
  const int*   eidx   = (const int*)d_in[1];
  const float* eattr  = (const float*)d_in[2];
  const float* gamma  = (const float*)d_in[3];
  const float* beta   = (const float*)d_in[4];
  const float* embW   = (const float*)d_in[5];
  const float* embB   = (const float*)d_in[6];
  const float* lnS    = (const float*)d_in[7];
  const float* lnB    = (const float*)d_in[8];
  const float* gatW   = (const float*)d_in[9];
  const float* attS   = (const float*)d_in[10];
  const float* attD   = (const float*)d_in[11];
  const float* gatWe  = (const float*)d_in[12];
  const float* attE   = (const float*)d_in[13];
  const float* gatB   = (const float*)d_in[14];
  const float* hW1    = (const float*)d_in[15];
  const float* hB1    = (const float*)d_in[16];
  const float* hW2    = (const float*)d_in[17];
  const float* hB2    = (const float*)d_in[18];
  float* out = (float*)d_out;

  int N = in_sizes[0] / DD;
  int E = in_sizes[1] / 2;
  int L = in_sizes[3] / DD;
  int Npad = (N + 63) & ~63;

  const int* srcA = eidx;
  const int* dstA = eidx + E;

  float* ws = (float*)d_ws;
  float* ea_sum  = ws + 0;
  float* we_att  = ws + 64;
  float* al_self = ws + 1024;
  float* ws_att  = ws + 2048;
  size_t o = 8192;
  int* deg    = (int*)(ws + o); o += N;
  int* offs   = (int*)(ws + o); o += N + 1;
  int* cursor = (int*)(ws + o); o += N;
  int* csrc   = (int*)(ws + o); o += E;
  int* posOf  = (int*)(ws + o); o += E;
  o = (o + 255) & ~(size_t)255;
  unsigned short* Bt  = (unsigned short*)(ws + o); o += (size_t)L*DD*HDIM/2;
  unsigned short* Bh  = (unsigned short*)(ws + o); o += 8*64*8/2;
  unsigned short* Wte = (unsigned short*)(ws + o); o += DD*DD/2;
  unsigned short* Bhd = (unsigned short*)(ws + o); o += 256*DD/2;
  unsigned short* xbf = (unsigned short*)(ws + o); o += (size_t)N*DD/2;
  unsigned short* hm_bf = (unsigned short*)(ws + o); o += (size_t)N*DD/2;
  float* al_s  = ws + o; o += (size_t)N*4;
  float* al_d  = ws + o; o += (size_t)N*4;
  unsigned short* eap = (unsigned short*)(ws + o); o += (size_t)E*EFEAT/2;
  float* ale   = ws + o; o += (size_t)L*E*4;
  unsigned short* z = (unsigned short*)(ws + o); o += (size_t)Npad*HDIM/2;
  unsigned short* hbf  = hm_bf;
  unsigned short* pbuf = z;

  hipMemsetAsync(ea_sum, 0, EFEAT*sizeof(float), stream);
  hipMemsetAsync(deg, 0, (size_t)N*sizeof(int), stream);
  ea_sum4_kernel<<<1024, 256, 0, stream>>>(eattr, ea_sum, E);
  hist_kernel<<<(E + 255)/256, 256, 0, stream>>>(dstA, deg, E);
  scan_kernel<<<1, 1024, 0, stream>>>(deg, offs, N);
  hipMemcpyAsync(cursor, offs, (size_t)N*sizeof(int), hipMemcpyDeviceToDevice, stream);
  scatter_kernel<<<(E + 255)/256, 256, 0, stream>>>(dstA, srcA, cursor, csrc, posOf, E);
  eap_prep_kernel<<<(E*8 + 255)/256, 256, 0, stream>>>(eattr, posOf, eap, E);
  fold_ws_kernel<<<(L*DD*8 + 3)/4, 256, 0, stream>>>(gatW, attS, attD, ws_att, L);
  fold_we_kernel<<<(L*EFEAT*NHEAD + 3)/4, 256, 0, stream>>>(gatWe, attE, we_att, L);
  fold_self_kernel<<<1, 64, 0, stream>>>(we_att, ea_sum, 1.0f/(float)E, al_self, L);
  bt_prep_kernel<<<L*NHEAD*16, 256, 0, stream>>>(gatW, Bt, L*NHEAD);
  embwt_prep_kernel<<<(DD*DD + 255)/256, 256, 0, stream>>>(embW, Wte);
  w1ab_prep_kernel<<<(256*DD + 255)/256, 256, 0, stream>>>(hW1, Bhd);
  w1c_prep_kernel<<<(8*64*8 + 255)/256, 256, 0, stream>>>(hW1 + 2*DD*DD, Bh);
  bf16_conv_kernel<<<(N*DD/4 + 255)/256, 256, 0, stream>>>(x, xbf, N*DD/4);
  ale_prep_kernel<<<(E + 255)/256, 256, 0, stream>>>(eap, we_att, ale, E, L);

  // embed + LN/FiLM/al (layer 0)
  gemm_fused_kernel<128,128><<<(N + 63)/64, 256, 0, stream>>>(
      xbf, Wte, embB, 1.0f, 0, 0, lnS, lnB, gamma, beta, ws_att,
      hm_bf, al_s, al_d, nullptr, N);

  for (int l = 0; l < L; l++){
    aggregate4_kernel<<<N, 64, 0, stream>>>(hm_bf, ale + (size_t)l*E*4,
        al_s, al_d, al_self + (size_t)l*NHEAD, offs, csrc, z, N);
    if (l < L - 1){
      gemm_fused_kernel<512,128><<<(N + 15)/16, 256, 0, stream>>>(
          z, Bt + (size_t)l*DD*HDIM, gatB + (size_t)l*DD, 0.25f, 1, 0,
          lnS + (l+1)*DD, lnB + (l+1)*DD, gamma + (l+1)*DD, beta + (l+1)*DD,
          ws_att + (size_t)(l+1)*DD*8, hm_bf, al_s, al_d, nullptr, N);
    } else {
      gemm_fused_kernel<512,128><<<(N + 15)/16, 256, 0, stream>>>(
          z, Bt + (size_t)l*DD*HDIM, gatB + (size_t)l*DD, 0.25f, 1, 1,
          nullptr, nullptr, nullptr, nullptr, nullptr,
          nullptr, nullptr, nullptr, hbf, N);
    }
  }

  // head pre-projection: pbuf[N,256] = hbf @ [W1a|W1b] (+hB1 on cols<128)
  gemm_fused_kernel<128,256><<<(N + 63)/64, 256, 0, stream>>>(
      hbf, Bhd, hB1, 1.0f, 0, 1, nullptr, nullptr, nullptr, nullptr, nullptr,
      nullptr, nullptr, nullptr, pbuf, N);

  head_mfma_kernel<<<(E + 63)/64, 256, 0, stream>>>(eap, posOf, Bh, pbuf,
      hW2, hB2, srcA, dstA, out, E);
}

// Round 4
// 641.750 us; speedup vs baseline: 1.1097x; 1.1097x over previous
//
#include <hip/hip_runtime.h>

#define DD 128      // GNN_DIM == NODE_FEAT
#define HDIM 512    // H * D
#define EFEAT 32
#define NHEAD 4

typedef short s16x8 __attribute__((ext_vector_type(8)));
typedef float f32x4 __attribute__((ext_vector_type(4)));

__device__ __forceinline__ float lrelu(float x){ return x > 0.f ? x : 0.2f*x; }

__device__ __forceinline__ unsigned short f2bf(float f){
  unsigned u = __float_as_uint(f);
  unsigned r = (u + 0x7FFFu + ((u >> 16) & 1u)) >> 16;
  return (unsigned short)r;
}
__device__ __forceinline__ float bf2f(unsigned short u){
  return __uint_as_float(((unsigned)u) << 16);
}

__device__ __forceinline__ float waveReduceSum(float v){
  #pragma unroll
  for (int m = 1; m < 64; m <<= 1) v += __shfl_xor(v, m, 64);
  return v;
}
__device__ __forceinline__ float quadReduceSum(float v){
  v += __shfl_xor(v, 1, 64); v += __shfl_xor(v, 2, 64);
  v += __shfl_xor(v, 4, 64); v += __shfl_xor(v, 8, 64);
  return v;
}

// ---------------- edge-attr column sums (float4, saturating grid) ----------------
__global__ __launch_bounds__(256) void ea_sum4_kernel(const float* __restrict__ ea,
                                                      float* __restrict__ ea_sum, int E){
  __shared__ float s[EFEAT];
  int t = threadIdx.x;
  if (t < EFEAT) s[t] = 0.f;
  __syncthreads();
  int nvec = E*8;
  float4 acc = make_float4(0.f, 0.f, 0.f, 0.f);
  for (int i = blockIdx.x*256 + t; i < nvec; i += gridDim.x*256){
    float4 v = *((const float4*)ea + i);
    acc.x += v.x; acc.y += v.y; acc.z += v.z; acc.w += v.w;
  }
  int cg = (t & 7)*4;
  atomicAdd(&s[cg + 0], acc.x); atomicAdd(&s[cg + 1], acc.y);
  atomicAdd(&s[cg + 2], acc.z); atomicAdd(&s[cg + 3], acc.w);
  __syncthreads();
  if (t < EFEAT) atomicAdd(&ea_sum[t], s[t]);
}

// ---------------- CSR build over dst ----------------
__global__ void hist_kernel(const int* __restrict__ dst, int* __restrict__ deg, int E){
  int e = blockIdx.x*blockDim.x + threadIdx.x;
  if (e < E) atomicAdd(&deg[dst[e]], 1);
}

__global__ void scan_kernel(const int* __restrict__ deg, int* __restrict__ offs, int N){
  __shared__ int s[1024];
  int t = threadIdx.x;
  int chunk = (N + 1023) >> 10;
  int b = t*chunk, e = min(b + chunk, N);
  int sum = 0;
  for (int i = b; i < e; i++) sum += deg[i];
  s[t] = sum;
  __syncthreads();
  for (int d = 1; d < 1024; d <<= 1){
    int x = (t >= d) ? s[t - d] : 0;
    __syncthreads();
    s[t] += x;
    __syncthreads();
  }
  int run = s[t] - sum;
  for (int i = b; i < e; i++){ offs[i] = run; run += deg[i]; }
  if (t == 1023) offs[N] = s[1023];
}

__global__ void scatter_kernel(const int* __restrict__ dst, const int* __restrict__ src,
                               int* __restrict__ cursor, int* __restrict__ csrc,
                               int* __restrict__ posOf, int E){
  int e = blockIdx.x*blockDim.x + threadIdx.x;
  if (e < E){
    int d = dst[e];
    int p = atomicAdd(&cursor[d], 1);
    csrc[p] = src[e];
    posOf[e] = p;
  }
}

// ---------------- convert edge attrs, scatter into CSR order (bf16) ------------
__global__ void eap_prep_kernel(const float* __restrict__ ea, const int* __restrict__ posOf,
                                unsigned short* __restrict__ eap, int E){
  int idx = blockIdx.x*blockDim.x + threadIdx.x;
  int e = idx >> 3, q = idx & 7;
  if (e >= E) return;
  int p = posOf[e];
  float4 v = *((const float4*)(ea + (size_t)e*EFEAT) + q);
  ushort4 u = make_ushort4(f2bf(v.x), f2bf(v.y), f2bf(v.z), f2bf(v.w));
  *((ushort4*)(eap + (size_t)p*EFEAT) + q) = u;
}

// ---------------- per-edge attention logits for ALL layers (CSR order) ---------
__global__ __launch_bounds__(256) void ale_prep_kernel(
    const unsigned short* __restrict__ eap, const float* __restrict__ we_att,
    float* __restrict__ ale, int E, int L){
  __shared__ float sea[256][33];
  __shared__ float swe[6*EFEAT*NHEAD];
  int t = threadIdx.x;
  for (int i = t; i < L*EFEAT*NHEAD; i += 256) swe[i] = we_att[i];
  size_t p0 = (size_t)blockIdx.x*256;
  int navail = min(256, E - (int)p0);
  for (int i = t; i < navail*4; i += 256){
    uint4 v = *((const uint4*)(eap + p0*EFEAT) + i);
    int el = i >> 2, q = i & 3;
    unsigned arr[4] = {v.x, v.y, v.z, v.w};
    #pragma unroll
    for (int j = 0; j < 4; j++){
      sea[el][q*8 + j*2]     = bf2f((unsigned short)(arr[j] & 0xffff));
      sea[el][q*8 + j*2 + 1] = bf2f((unsigned short)(arr[j] >> 16));
    }
  }
  __syncthreads();
  if ((int)p0 + t >= E) return;
  float ea[EFEAT];
  #pragma unroll
  for (int f = 0; f < EFEAT; f++) ea[f] = sea[t][f];
  size_t p = p0 + t;
  for (int l = 0; l < L; l++){
    float a0 = 0.f, a1 = 0.f, a2 = 0.f, a3 = 0.f;
    const float* w = &swe[l*EFEAT*NHEAD];
    #pragma unroll
    for (int f = 0; f < EFEAT; f++){
      float v = ea[f];
      a0 += v*w[f*4 + 0]; a1 += v*w[f*4 + 1];
      a2 += v*w[f*4 + 2]; a3 += v*w[f*4 + 3];
    }
    *(float4*)&ale[((size_t)l*E + p)*4] = make_float4(a0, a1, a2, a3);
  }
}

// ---------------- fp32 -> bf16 convert (float4 -> ushort4) ----------------
__global__ void bf16_conv_kernel(const float* __restrict__ in,
                                 unsigned short* __restrict__ out, int nvec){
  int i = blockIdx.x*blockDim.x + threadIdx.x;
  if (i >= nvec) return;
  float4 v = *((const float4*)in + i);
  *((ushort4*)out + i) = make_ushort4(f2bf(v.x), f2bf(v.y), f2bf(v.z), f2bf(v.w));
}

// ---------------- parallel folds: wave per output ----------------
__global__ __launch_bounds__(256) void fold_ws_kernel(const float* __restrict__ gat_W,
    const float* __restrict__ att_src, const float* __restrict__ att_dst,
    float* __restrict__ ws_att, int L){
  int wave = threadIdx.x >> 6, lane = threadIdx.x & 63;
  int idx = blockIdx.x*4 + wave;
  if (idx >= L*DD*8) return;
  int j = idx & 7; int k = (idx >> 3) & 127; int l = idx >> 10;
  int h = j & 3;
  const float* att = (j < 4) ? att_src : att_dst;
  const float* av = att + (size_t)(l*NHEAD + h)*DD;
  const float* Wl = gat_W + (size_t)l*DD*HDIM + (size_t)k*HDIM + h*DD;
  float acc = Wl[lane]*av[lane] + Wl[lane + 64]*av[lane + 64];
  acc = waveReduceSum(acc);
  if (lane == 0) ws_att[idx] = acc;
}

__global__ __launch_bounds__(256) void fold_we_kernel(const float* __restrict__ gat_We,
    const float* __restrict__ att_edge, float* __restrict__ we_att, int L){
  int wave = threadIdx.x >> 6, lane = threadIdx.x & 63;
  int idx = blockIdx.x*4 + wave;
  if (idx >= L*EFEAT*NHEAD) return;
  int h = idx & 3; int f = (idx >> 2) & 31; int l = idx >> 7;
  const float* av = att_edge + (size_t)(l*NHEAD + h)*DD;
  const float* Wel = gat_We + (size_t)l*EFEAT*HDIM + (size_t)f*HDIM + h*DD;
  float acc = Wel[lane]*av[lane] + Wel[lane + 64]*av[lane + 64];
  acc = waveReduceSum(acc);
  if (lane == 0) we_att[idx] = acc;
}

__global__ void fold_self_kernel(const float* __restrict__ we_att,
    const float* __restrict__ ea_sum, float invE, float* __restrict__ al_self, int L){
  int t = threadIdx.x;
  if (t >= L*NHEAD) return;
  int h = t & 3; int l = t >> 2;
  float acc = 0.f;
  for (int f = 0; f < EFEAT; f++) acc += ea_sum[f]*invE * we_att[(l*EFEAT + f)*NHEAD + h];
  al_self[t] = acc;
}

// ---------------- gat_W -> bf16 Bt[l][d][h*128+k], LDS-tiled transpose ----------------
__global__ __launch_bounds__(256) void bt_prep_kernel(const float* __restrict__ gat_W,
                                                      unsigned short* __restrict__ Bt, int LH){
  __shared__ float tile[32][33];
  int blk = blockIdx.x;
  int lh = blk >> 4;
  if (lh >= LH) return;
  int tl = blk & 15;
  int k0 = (tl & 3)*32, d0 = (tl >> 2)*32;
  int l = lh >> 2, h = lh & 3;
  const float* in = gat_W + (size_t)l*DD*HDIM + h*DD;
  unsigned short* outp = Bt + (size_t)l*DD*HDIM + h*DD;
  int tx = threadIdx.x & 31, ty = threadIdx.x >> 5;
  #pragma unroll
  for (int i = 0; i < 4; i++){
    int k = k0 + ty + i*8;
    tile[ty + i*8][tx] = in[(size_t)k*HDIM + d0 + tx];
  }
  __syncthreads();
  #pragma unroll
  for (int i = 0; i < 4; i++){
    int d = d0 + ty + i*8;
    outp[(size_t)d*HDIM + k0 + tx] = f2bf(tile[tx][ty + i*8]);
  }
}

// ---------------- embW -> bf16 transposed [128][128] ----------------
__global__ void embwt_prep_kernel(const float* __restrict__ embW,
                                  unsigned short* __restrict__ Wt){
  int i = blockIdx.x*blockDim.x + threadIdx.x;
  if (i >= DD*DD) return;
  int n = i >> 7, k = i & 127;
  Wt[i] = f2bf(embW[(size_t)k*DD + n]);
}

// ---------------- [W1a | W1b] -> bf16 transposed [256][128] ----------------
__global__ void w1ab_prep_kernel(const float* __restrict__ hW1,
                                 unsigned short* __restrict__ Bhd){
  int i = blockIdx.x*blockDim.x + threadIdx.x;
  if (i >= 256*DD) return;
  int n = i >> 7, k = i & 127;
  float v = (n < 128) ? hW1[(size_t)k*DD + n] : hW1[(size_t)(128 + k)*DD + (n - 128)];
  Bhd[i] = f2bf(v);
}

// ---------------- W1c -> MFMA B-fragment layout: Bh[c][lane][j] ----------------
__global__ void w1c_prep_kernel(const float* __restrict__ W1c, unsigned short* __restrict__ Bh){
  int i = blockIdx.x*blockDim.x + threadIdx.x;
  if (i >= 8*64*8) return;
  int j = i & 7, lane = (i >> 3) & 63, c = i >> 9;
  int ln15 = lane & 15, quad = lane >> 4;
  int k = quad*8 + j, n = c*16 + ln15;
  Bh[i] = f2bf(W1c[(size_t)k*DD + n]);
}

// ---------------- B [NOUT][KD] row-major -> MFMA fragment-linear ----------------
// Bfl[((ks*NC + c)*64 + lane)*8 + j] = Bmat[c*16 + (lane&15)][ks*32 + (lane>>4)*8 + j]
// Makes the GEMM's per-wave B loads perfectly coalesced (1KB contiguous per instr).
__global__ void bfl_prep_kernel(const unsigned short* __restrict__ Bmat,
                                unsigned short* __restrict__ Bfl, int KD, int NOUT){
  int idx = blockIdx.x*blockDim.x + threadIdx.x;   // one per uint4 (8 bf16)
  int total = (KD*NOUT) >> 3;
  if (idx >= total) return;
  int lane = idx & 63;
  int rest = idx >> 6;
  int NC = NOUT >> 4;
  int c = rest % NC, ks = rest / NC;
  int row = c*16 + (lane & 15);
  int k0  = ks*32 + (lane >> 4)*8;
  *(uint4*)(Bfl + (size_t)idx*8) = *(const uint4*)(Bmat + (size_t)row*KD + k0);
}

// ---------------- unified MFMA GEMM + fused epilogues ----------------
// Barrier-free structure: wave per 16 rows (4 indep waves/block), B fragments
// loaded DIRECTLY from global in fragment-linear layout (Bfl) -- no LDS staging,
// no per-chunk barriers (the R2/R3 latency killer). B is L2-resident (131KB).
// mode==0 keeps a single entry barrier to stage epilogue params into LDS.
template<int KD, int NOUT>
__global__ __launch_bounds__(256, 2) void gemm_fused_kernel(
    const unsigned short* __restrict__ A, const unsigned short* __restrict__ Bfl,
    const float* __restrict__ bias, float scale, int relu, int mode,
    const float* __restrict__ ln_scale, const float* __restrict__ ln_bias,
    const float* __restrict__ gamma, const float* __restrict__ beta,
    const float* __restrict__ ws_att,
    unsigned short* __restrict__ hm_bf, float* __restrict__ al_s,
    float* __restrict__ al_d, unsigned short* __restrict__ outbf, int N){
  constexpr int NC = NOUT/16;
  constexpr int NKS = KD/32;
  __shared__ float s_att[8*DD];
  __shared__ float sP[4][DD];
  int t = threadIdx.x;
  if (mode == 0){
    for (int i = t; i < DD*8; i += 256){
      int col = i & 127, j = i >> 7;
      s_att[j*DD + col] = ws_att[col*8 + j];
    }
    for (int i = t; i < DD; i += 256){
      sP[0][i] = ln_scale[i]; sP[1][i] = ln_bias[i];
      sP[2][i] = gamma[i];    sP[3][i] = beta[i];
    }
    __syncthreads();
  }
  int wave = t >> 6, lane = t & 63;
  int ln15 = lane & 15, quad = lane >> 4;
  int row0 = (blockIdx.x*4 + wave)*16;
  int arow = row0 + ln15;
  if (arow > N - 1) arow = N - 1;
  const unsigned short* aptr = A + (size_t)arow*KD + quad*8;
  const unsigned short* bptr = Bfl + (size_t)lane*8;

  f32x4 acc[NC];
  #pragma unroll
  for (int c = 0; c < NC; c++) acc[c] = (f32x4)(0.f);

  #pragma unroll
  for (int ks = 0; ks < NKS; ks++){
    s16x8 af = *(const s16x8*)(aptr + ks*32);
    #pragma unroll
    for (int c = 0; c < NC; c++){
      s16x8 b = *(const s16x8*)(bptr + (size_t)(ks*NC + c)*512);
      acc[c] = __builtin_amdgcn_mfma_f32_16x16x32_bf16(af, b, acc[c], 0, 0, 0);
    }
  }

  float bv[NC];
  #pragma unroll
  for (int c = 0; c < NC; c++){
    if constexpr (NOUT == 256) bv[c] = (c < 8) ? bias[c*16 + ln15] : 0.f;
    else bv[c] = bias[c*16 + ln15];
  }

  #pragma unroll
  for (int r = 0; r < 4; r++){
    int row = row0 + quad*4 + r;
    bool valid = (row < N);
    float hv[NC];
    #pragma unroll
    for (int c = 0; c < NC; c++){
      float v = scale*acc[c][r] + bv[c];
      hv[c] = relu ? fmaxf(v, 0.f) : v;
    }
    if (mode == 1){
      if (valid){
        if constexpr (NOUT == 256){
          // head layout: pbuf[row][ln15*8 + c] (first 128) / [128 + ln15*8 + c-8]
          unsigned short us[16];
          #pragma unroll
          for (int c = 0; c < 16; c++) us[c] = f2bf(hv[c]);
          uint4 va, vb;
          va.x = (unsigned)us[0] | ((unsigned)us[1] << 16);
          va.y = (unsigned)us[2] | ((unsigned)us[3] << 16);
          va.z = (unsigned)us[4] | ((unsigned)us[5] << 16);
          va.w = (unsigned)us[6] | ((unsigned)us[7] << 16);
          vb.x = (unsigned)us[8] | ((unsigned)us[9] << 16);
          vb.y = (unsigned)us[10] | ((unsigned)us[11] << 16);
          vb.z = (unsigned)us[12] | ((unsigned)us[13] << 16);
          vb.w = (unsigned)us[14] | ((unsigned)us[15] << 16);
          *(uint4*)(outbf + (size_t)row*256 + ln15*8) = va;
          *(uint4*)(outbf + (size_t)row*256 + 128 + ln15*8) = vb;
        } else {
          #pragma unroll
          for (int c = 0; c < NC; c++)
            outbf[(size_t)row*NOUT + c*16 + ln15] = f2bf(hv[c]);
        }
      }
      continue;
    }
    if constexpr (NOUT == 128){
      float sum = 0.f;
      #pragma unroll
      for (int c = 0; c < NC; c++) sum += hv[c];
      sum = quadReduceSum(sum);
      float mu = sum * (1.f/128.f);
      float vs = 0.f;
      #pragma unroll
      for (int c = 0; c < NC; c++){ float d = hv[c] - mu; vs += d*d; }
      vs = quadReduceSum(vs);
      float rstd = rsqrtf(vs*(1.f/128.f) + 1e-5f);
      float m[NC];
      #pragma unroll
      for (int c = 0; c < NC; c++){
        int col = c*16 + ln15;
        float hn = (hv[c] - mu)*rstd*sP[0][col] + sP[1][col];
        m[c] = sP[2][col]*hn + sP[3][col];
        if (valid) hm_bf[(size_t)row*DD + col] = f2bf(m[c]);
      }
      float alv[8];
      #pragma unroll
      for (int j = 0; j < 8; j++){
        float a = 0.f;
        #pragma unroll
        for (int c = 0; c < NC; c++) a += m[c]*s_att[j*DD + c*16 + ln15];
        alv[j] = quadReduceSum(a);
      }
      if (ln15 == 0 && valid){
        *(float4*)&al_s[(size_t)row*4] = make_float4(alv[0], alv[1], alv[2], alv[3]);
        *(float4*)&al_d[(size_t)row*4] = make_float4(alv[4], alv[5], alv[6], alv[7]);
      }
    }
  }
}

// ---------------- fused softmax + weighted aggregation (block per node) --------
__global__ __launch_bounds__(64) void aggregate4_kernel(
    const unsigned short* __restrict__ hm_bf, const float* __restrict__ ale,
    const float* __restrict__ al_s, const float* __restrict__ al_d,
    const float* __restrict__ al_self4, const int* __restrict__ offs,
    const int* __restrict__ csrc, unsigned short* __restrict__ z, int N){
  __shared__ float sw0[64], sw1[64], sw2[64], sw3[64];
  __shared__ int ssrc[64];
  int n = blockIdx.x, t = threadIdx.x;
  int beg = offs[n], end = offs[n + 1];
  float4 aslf = *(const float4*)al_self4;
  float4 asn = *(const float4*)&al_s[(size_t)n*4];
  float4 adn = *(const float4*)&al_d[(size_t)n*4];
  float e0 = __expf(lrelu(asn.x + adn.x + aslf.x));
  float e1 = __expf(lrelu(asn.y + adn.y + aslf.y));
  float e2 = __expf(lrelu(asn.z + adn.z + aslf.z));
  float e3 = __expf(lrelu(asn.w + adn.w + aslf.w));
  ushort2 hv = *((const ushort2*)(hm_bf + (size_t)n*DD) + t);
  float h0 = bf2f(hv.x), h1 = bf2f(hv.y);
  float ac00 = e0*h0, ac01 = e0*h1;
  float ac10 = e1*h0, ac11 = e1*h1;
  float ac20 = e2*h0, ac21 = e2*h1;
  float ac30 = e3*h0, ac31 = e3*h1;
  float den0 = e0, den1 = e1, den2 = e2, den3 = e3;
  for (int c0 = beg; c0 < end; c0 += 64){
    int p = c0 + t;
    if (p < end){
      int s = csrc[p];
      float4 ae = *(const float4*)&ale[(size_t)p*4];
      float4 as = *(const float4*)&al_s[(size_t)s*4];
      sw0[t] = __expf(lrelu(as.x + adn.x + ae.x));
      sw1[t] = __expf(lrelu(as.y + adn.y + ae.y));
      sw2[t] = __expf(lrelu(as.z + adn.z + ae.z));
      sw3[t] = __expf(lrelu(as.w + adn.w + ae.w));
      ssrc[t] = s;
    }
    __syncthreads();
    int cnt = min(64, end - c0);
    int i = 0;
    for (; i + 4 <= cnt; i += 4){   // 4-deep: keep 4 scattered row-loads in flight
      int sA = ssrc[i], sB = ssrc[i + 1], sC = ssrc[i + 2], sD = ssrc[i + 3];
      ushort2 vA = *((const ushort2*)(hm_bf + (size_t)sA*DD) + t);
      ushort2 vB = *((const ushort2*)(hm_bf + (size_t)sB*DD) + t);
      ushort2 vC = *((const ushort2*)(hm_bf + (size_t)sC*DD) + t);
      ushort2 vD = *((const ushort2*)(hm_bf + (size_t)sD*DD) + t);
      float wA0 = sw0[i], wA1 = sw1[i], wA2 = sw2[i], wA3 = sw3[i];
      float wB0 = sw0[i+1], wB1 = sw1[i+1], wB2 = sw2[i+1], wB3 = sw3[i+1];
      float wC0 = sw0[i+2], wC1 = sw1[i+2], wC2 = sw2[i+2], wC3 = sw3[i+2];
      float wD0 = sw0[i+3], wD1 = sw1[i+3], wD2 = sw2[i+3], wD3 = sw3[i+3];
      float vA0 = bf2f(vA.x), vA1 = bf2f(vA.y);
      float vB0 = bf2f(vB.x), vB1 = bf2f(vB.y);
      float vC0 = bf2f(vC.x), vC1 = bf2f(vC.y);
      float vD0 = bf2f(vD.x), vD1 = bf2f(vD.y);
      ac00 += wA0*vA0 + wB0*vB0 + wC0*vC0 + wD0*vD0;
      ac01 += wA0*vA1 + wB0*vB1 + wC0*vC1 + wD0*vD1;
      ac10 += wA1*vA0 + wB1*vB0 + wC1*vC0 + wD1*vD0;
      ac11 += wA1*vA1 + wB1*vB1 + wC1*vC1 + wD1*vD1;
      ac20 += wA2*vA0 + wB2*vB0 + wC2*vC0 + wD2*vD0;
      ac21 += wA2*vA1 + wB2*vB1 + wC2*vC1 + wD2*vD1;
      ac30 += wA3*vA0 + wB3*vB0 + wC3*vC0 + wD3*vD0;
      ac31 += wA3*vA1 + wB3*vB1 + wC3*vC1 + wD3*vD1;
      den0 += wA0 + wB0 + wC0 + wD0; den1 += wA1 + wB1 + wC1 + wD1;
      den2 += wA2 + wB2 + wC2 + wD2; den3 += wA3 + wB3 + wC3 + wD3;
    }
    for (; i < cnt; i++){
      int s = ssrc[i];
      float w0 = sw0[i], w1 = sw1[i], w2 = sw2[i], w3 = sw3[i];
      ushort2 v2 = *((const ushort2*)(hm_bf + (size_t)s*DD) + t);
      float v0 = bf2f(v2.x), v1 = bf2f(v2.y);
      ac00 += w0*v0; ac01 += w0*v1;
      ac10 += w1*v0; ac11 += w1*v1;
      ac20 += w2*v0; ac21 += w2*v1;
      ac30 += w3*v0; ac31 += w3*v1;
      den0 += w0; den1 += w1; den2 += w2; den3 += w3;
    }
    __syncthreads();
  }
  float r0 = 1.f/(den0 + 1e-16f), r1 = 1.f/(den1 + 1e-16f);
  float r2 = 1.f/(den2 + 1e-16f), r3 = 1.f/(den3 + 1e-16f);
  size_t zb = (size_t)n*HDIM;
  ushort2* zp = (ushort2*)(z + zb);
  zp[0*64 + t] = make_ushort2(f2bf(ac00*r0), f2bf(ac01*r0));
  zp[1*64 + t] = make_ushort2(f2bf(ac10*r1), f2bf(ac11*r1));
  zp[2*64 + t] = make_ushort2(f2bf(ac20*r2), f2bf(ac21*r2));
  zp[3*64 + t] = make_ushort2(f2bf(ac30*r3), f2bf(ac31*r3));
}

// ---------------- MFMA edge head: out[e] = relu(p[s]+p[d]+ea@W1c)@W2 + b2 ------------
__global__ __launch_bounds__(256) void head_mfma_kernel(
    const unsigned short* __restrict__ eap, const int* __restrict__ posOf,
    const unsigned short* __restrict__ Bh, const unsigned short* __restrict__ pbuf,
    const float* __restrict__ W2, const float* __restrict__ b2,
    const int* __restrict__ srcA, const int* __restrict__ dstA,
    float* __restrict__ out, int E){
  int t = threadIdx.x;
  int wave = t >> 6, lane = t & 63;
  int ln15 = lane & 15, quad = lane >> 4;
  int e0 = (blockIdx.x*4 + wave)*16;
  if (e0 >= E) return;
  int arow = e0 + ln15;
  if (arow > E - 1) arow = E - 1;
  int ap = posOf[arow];
  s16x8 a = *(const s16x8*)(eap + (size_t)ap*EFEAT + quad*8);
  f32x4 acc[8];
  #pragma unroll
  for (int c = 0; c < 8; c++){
    s16x8 b = *(const s16x8*)(Bh + ((size_t)c*64 + lane)*8);
    acc[c] = __builtin_amdgcn_mfma_f32_16x16x32_bf16(a, b, (f32x4)(0.f), 0, 0, 0);
  }
  float w2v[8];
  #pragma unroll
  for (int c = 0; c < 8; c++) w2v[c] = W2[c*16 + ln15];
  float res[4];
  #pragma unroll
  for (int r = 0; r < 4; r++){
    int e = e0 + quad*4 + r;
    int ec = (e < E) ? e : E - 1;
    int s = srcA[ec], d = dstA[ec];
    s16x8 pa = *(const s16x8*)(pbuf + (size_t)s*256 + ln15*8);
    s16x8 pb = *(const s16x8*)(pbuf + (size_t)d*256 + 128 + ln15*8);
    float sum = 0.f;
    #pragma unroll
    for (int c = 0; c < 8; c++){
      float q = acc[c][r] + bf2f((unsigned short)pa[c]) + bf2f((unsigned short)pb[c]);
      sum += fmaxf(q, 0.f) * w2v[c];
    }
    res[r] = sum;
  }
  #pragma unroll
  for (int r = 0; r < 4; r++){
    float v = res[r];
    v += __shfl_xor(v, 1, 64); v += __shfl_xor(v, 2, 64);
    v += __shfl_xor(v, 4, 64); v += __shfl_xor(v, 8, 64);
    res[r] = v;
  }
  if (ln15 == 0){
    float bb = b2[0];
    #pragma unroll
    for (int r = 0; r < 4; r++){
      int e = e0 + quad*4 + r;
      if (e < E) out[e] = res[r] + bb;
    }
  }
}

extern "C" void kernel_launch(void* const* d_in, const int* in_sizes, int n_in,
                              void* d_out, int out_size, void* d_ws, size_t ws_size,
                              hipStream_t stream){
  const float* x      = (const float*)d_in[0];
  const int*   eidx   = (const int*)d_in[1];
  const float* eattr  = (const float*)d_in[2];
  const float* gamma  = (const float*)d_in[3];
  const float* beta   = (const float*)d_in[4];
  const float* embW   = (const float*)d_in[5];
  const float* embB   = (const float*)d_in[6];
  const float* lnS    = (const float*)d_in[7];
  const float* lnB    = (const float*)d_in[8];
  const float* gatW   = (const float*)d_in[9];
  const float* attS   = (const float*)d_in[10];
  const float* attD   = (const float*)d_in[11];
  const float* gatWe  = (const float*)d_in[12];
  const float* attE   = (const float*)d_in[13];
  const float* gatB   = (const float*)d_in[14];
  const float* hW1    = (const float*)d_in[15];
  const float* hB1    = (const float*)d_in[16];
  const float* hW2    = (const float*)d_in[17];
  const float* hB2    = (const float*)d_in[18];
  float* out = (float*)d_out;

  int N = in_sizes[0] / DD;
  int E = in_sizes[1] / 2;
  int L = in_sizes[3] / DD;
  int Npad = (N + 63) & ~63;

  const int* srcA = eidx;
  const int* dstA = eidx + E;

  float* ws = (float*)d_ws;
  float* ea_sum  = ws + 0;
  float* we_att  = ws + 64;
  float* al_self = ws + 1024;
  float* ws_att  = ws + 2048;
  size_t o = 8192;
  int* deg    = (int*)(ws + o); o += N;
  int* offs   = (int*)(ws + o); o += N + 1;
  int* cursor = (int*)(ws + o); o += N;
  int* csrc   = (int*)(ws + o); o += E;
  int* posOf  = (int*)(ws + o); o += E;
  o = (o + 255) & ~(size_t)255;
  unsigned short* Bt  = (unsigned short*)(ws + o); o += (size_t)L*DD*HDIM/2;
  unsigned short* Btf = (unsigned short*)(ws + o); o += (size_t)L*DD*HDIM/2;
  unsigned short* Bh  = (unsigned short*)(ws + o); o += 8*64*8/2;
  unsigned short* Wte = (unsigned short*)(ws + o); o += DD*DD/2;
  unsigned short* Wtef= (unsigned short*)(ws + o); o += DD*DD/2;
  unsigned short* Bhd = (unsigned short*)(ws + o); o += 256*DD/2;
  unsigned short* Bhdf= (unsigned short*)(ws + o); o += 256*DD/2;
  unsigned short* xbf = (unsigned short*)(ws + o); o += (size_t)N*DD/2;
  unsigned short* hm_bf = (unsigned short*)(ws + o); o += (size_t)N*DD/2;
  float* al_s  = ws + o; o += (size_t)N*4;
  float* al_d  = ws + o; o += (size_t)N*4;
  unsigned short* eap = (unsigned short*)(ws + o); o += (size_t)E*EFEAT/2;
  float* ale   = ws + o; o += (size_t)L*E*4;
  unsigned short* z = (unsigned short*)(ws + o); o += (size_t)Npad*HDIM/2;
  unsigned short* hbf  = hm_bf;
  unsigned short* pbuf = z;

  hipMemsetAsync(ea_sum, 0, EFEAT*sizeof(float), stream);
  hipMemsetAsync(deg, 0, (size_t)N*sizeof(int), stream);
  ea_sum4_kernel<<<1024, 256, 0, stream>>>(eattr, ea_sum, E);
  hist_kernel<<<(E + 255)/256, 256, 0, stream>>>(dstA, deg, E);
  scan_kernel<<<1, 1024, 0, stream>>>(deg, offs, N);
  hipMemcpyAsync(cursor, offs, (size_t)N*sizeof(int), hipMemcpyDeviceToDevice, stream);
  scatter_kernel<<<(E + 255)/256, 256, 0, stream>>>(dstA, srcA, cursor, csrc, posOf, E);
  eap_prep_kernel<<<(E*8 + 255)/256, 256, 0, stream>>>(eattr, posOf, eap, E);
  fold_ws_kernel<<<(L*DD*8 + 3)/4, 256, 0, stream>>>(gatW, attS, attD, ws_att, L);
  fold_we_kernel<<<(L*EFEAT*NHEAD + 3)/4, 256, 0, stream>>>(gatWe, attE, we_att, L);
  fold_self_kernel<<<1, 64, 0, stream>>>(we_att, ea_sum, 1.0f/(float)E, al_self, L);
  bt_prep_kernel<<<L*NHEAD*16, 256, 0, stream>>>(gatW, Bt, L*NHEAD);
  embwt_prep_kernel<<<(DD*DD + 255)/256, 256, 0, stream>>>(embW, Wte);
  w1ab_prep_kernel<<<(256*DD + 255)/256, 256, 0, stream>>>(hW1, Bhd);
  w1c_prep_kernel<<<(8*64*8 + 255)/256, 256, 0, stream>>>(hW1 + 2*DD*DD, Bh);
  bf16_conv_kernel<<<(N*DD/4 + 255)/256, 256, 0, stream>>>(x, xbf, N*DD/4);
  ale_prep_kernel<<<(E + 255)/256, 256, 0, stream>>>(eap, we_att, ale, E, L);
  // fragment-linear repacks (one-time)
  for (int l = 0; l < L; l++)
    bfl_prep_kernel<<<(DD*HDIM/8 + 255)/256, 256, 0, stream>>>(
        Bt + (size_t)l*DD*HDIM, Btf + (size_t)l*DD*HDIM, HDIM, DD);
  bfl_prep_kernel<<<(DD*DD/8 + 255)/256, 256, 0, stream>>>(Wte, Wtef, DD, DD);
  bfl_prep_kernel<<<(256*DD/8 + 255)/256, 256, 0, stream>>>(Bhd, Bhdf, DD, 256);

  // embed + LN/FiLM/al (layer 0)
  gemm_fused_kernel<128,128><<<(N + 63)/64, 256, 0, stream>>>(
      xbf, Wtef, embB, 1.0f, 0, 0, lnS, lnB, gamma, beta, ws_att,
      hm_bf, al_s, al_d, nullptr, N);

  for (int l = 0; l < L; l++){
    aggregate4_kernel<<<N, 64, 0, stream>>>(hm_bf, ale + (size_t)l*E*4,
        al_s, al_d, al_self + (size_t)l*NHEAD, offs, csrc, z, N);
    if (l < L - 1){
      gemm_fused_kernel<512,128><<<(N + 63)/64, 256, 0, stream>>>(
          z, Btf + (size_t)l*DD*HDIM, gatB + (size_t)l*DD, 0.25f, 1, 0,
          lnS + (l+1)*DD, lnB + (l+1)*DD, gamma + (l+1)*DD, beta + (l+1)*DD,
          ws_att + (size_t)(l+1)*DD*8, hm_bf, al_s, al_d, nullptr, N);
    } else {
      gemm_fused_kernel<512,128><<<(N + 63)/64, 256, 0, stream>>>(
          z, Btf + (size_t)l*DD*HDIM, gatB + (size_t)l*DD, 0.25f, 1, 1,
          nullptr, nullptr, nullptr, nullptr, nullptr,
          nullptr, nullptr, nullptr, hbf, N);
    }
  }

  // head pre-projection: pbuf[N,256] = hbf @ [W1a|W1b] (+hB1 on cols<128)
  gemm_fused_kernel<128,256><<<(N + 63)/64, 256, 0, stream>>>(
      hbf, Bhdf, hB1, 1.0f, 0, 1, nullptr, nullptr, nullptr, nullptr, nullptr,
      nullptr, nullptr, nullptr, pbuf, N);

  head_mfma_kernel<<<(E + 63)/64, 256, 0, stream>>>(eap, posOf, Bh, pbuf,
      hW2, hB2, srcA, dstA, out, E);
}

// Round 5
// 631.131 us; speedup vs baseline: 1.1283x; 1.0168x over previous
//
#include <hip/hip_runtime.h>

#define DD 128      // GNN_DIM == NODE_FEAT
#define HDIM 512    // H * D
#define EFEAT 32
#define NHEAD 4

typedef short s16x8 __attribute__((ext_vector_type(8)));
typedef float f32x4 __attribute__((ext_vector_type(4)));

__device__ __forceinline__ float lrelu(float x){ return x > 0.f ? x : 0.2f*x; }

__device__ __forceinline__ unsigned short f2bf(float f){
  unsigned u = __float_as_uint(f);
  unsigned r = (u + 0x7FFFu + ((u >> 16) & 1u)) >> 16;
  return (unsigned short)r;
}
__device__ __forceinline__ float bf2f(unsigned short u){
  return __uint_as_float(((unsigned)u) << 16);
}

__device__ __forceinline__ float waveReduceSum(float v){
  #pragma unroll
  for (int m = 1; m < 64; m <<= 1) v += __shfl_xor(v, m, 64);
  return v;
}
__device__ __forceinline__ float quadReduceSum(float v){
  v += __shfl_xor(v, 1, 64); v += __shfl_xor(v, 2, 64);
  v += __shfl_xor(v, 4, 64); v += __shfl_xor(v, 8, 64);
  return v;
}

// ---------------- CSR build over dst ----------------
__global__ void hist_kernel(const int* __restrict__ dst, int* __restrict__ deg, int E){
  int e = blockIdx.x*blockDim.x + threadIdx.x;
  if (e < E) atomicAdd(&deg[dst[e]], 1);
}

__global__ void scan_kernel(const int* __restrict__ deg, int* __restrict__ offs, int N){
  __shared__ int s[1024];
  int t = threadIdx.x;
  int chunk = (N + 1023) >> 10;
  int b = t*chunk, e = min(b + chunk, N);
  int sum = 0;
  for (int i = b; i < e; i++) sum += deg[i];
  s[t] = sum;
  __syncthreads();
  for (int d = 1; d < 1024; d <<= 1){
    int x = (t >= d) ? s[t - d] : 0;
    __syncthreads();
    s[t] += x;
    __syncthreads();
  }
  int run = s[t] - sum;
  for (int i = b; i < e; i++){ offs[i] = run; run += deg[i]; }
  if (t == 1023) offs[N] = s[1023];
}

__global__ void scatter_kernel(const int* __restrict__ dst, const int* __restrict__ src,
                               int* __restrict__ cursor, int* __restrict__ csrc,
                               int* __restrict__ posOf, int E){
  int e = blockIdx.x*blockDim.x + threadIdx.x;
  if (e < E){
    int d = dst[e];
    int p = atomicAdd(&cursor[d], 1);
    csrc[p] = src[e];
    posOf[e] = p;
  }
}

// ---------------- fused edge prep: eattr -> eap(bf16,CSR) + ale(all L) + ea_sum ----
// Single 51MB coalesced read of eattr replaces ea_sum4+eap_prep+ale_prep.
__global__ __launch_bounds__(256) void edge_all_kernel(
    const float* __restrict__ ea, const int* __restrict__ posOf,
    const float* __restrict__ we_att, unsigned short* __restrict__ eap,
    float* __restrict__ ale, float* __restrict__ ea_sum, int E, int L){
  __shared__ float sea[256][33];
  __shared__ float swe[6*EFEAT*NHEAD];
  __shared__ float ssum[EFEAT];
  int t = threadIdx.x;
  for (int i = t; i < L*EFEAT*NHEAD; i += 256) swe[i] = we_att[i];
  if (t < EFEAT) ssum[t] = 0.f;
  int e0 = blockIdx.x*256;
  int navail = min(256, E - e0);
  for (int i = t; i < navail*8; i += 256){
    float4 v = ((const float4*)(ea + (size_t)e0*EFEAT))[i];
    int el = i >> 3, q = i & 7;
    sea[el][q*4 + 0] = v.x; sea[el][q*4 + 1] = v.y;
    sea[el][q*4 + 2] = v.z; sea[el][q*4 + 3] = v.w;
  }
  __syncthreads();
  int e = e0 + t;
  bool ok = (e < E);
  float f[EFEAT];
  #pragma unroll
  for (int j = 0; j < EFEAT; j++) f[j] = 0.f;
  if (ok){
    #pragma unroll
    for (int j = 0; j < EFEAT; j++) f[j] = sea[t][j];
    int p = posOf[e];
    unsigned short us[EFEAT];
    #pragma unroll
    for (int j = 0; j < EFEAT; j++) us[j] = f2bf(f[j]);
    uint4* op = (uint4*)(eap + (size_t)p*EFEAT);
    #pragma unroll
    for (int q = 0; q < 4; q++){
      uint4 w;
      w.x = (unsigned)us[q*8+0] | ((unsigned)us[q*8+1] << 16);
      w.y = (unsigned)us[q*8+2] | ((unsigned)us[q*8+3] << 16);
      w.z = (unsigned)us[q*8+4] | ((unsigned)us[q*8+5] << 16);
      w.w = (unsigned)us[q*8+6] | ((unsigned)us[q*8+7] << 16);
      op[q] = w;
    }
    for (int l = 0; l < L; l++){
      float a0 = 0.f, a1 = 0.f, a2 = 0.f, a3 = 0.f;
      const float* w = &swe[l*EFEAT*NHEAD];
      #pragma unroll
      for (int j = 0; j < EFEAT; j++){
        float v = f[j];
        a0 += v*w[j*4 + 0]; a1 += v*w[j*4 + 1];
        a2 += v*w[j*4 + 2]; a3 += v*w[j*4 + 3];
      }
      *(float4*)&ale[((size_t)l*E + p)*4] = make_float4(a0, a1, a2, a3);
    }
  }
  // per-wave column sums (all threads participate in shuffles)
  int lane = t & 63;
  #pragma unroll
  for (int j = 0; j < EFEAT; j++){
    float v = waveReduceSum(f[j]);
    if (lane == j) atomicAdd(&ssum[j], v);
  }
  __syncthreads();
  if (t < EFEAT) atomicAdd(&ea_sum[t], ssum[t]);
}

// ---------------- fp32 -> bf16 convert (float4 -> ushort4) ----------------
__global__ void bf16_conv_kernel(const float* __restrict__ in,
                                 unsigned short* __restrict__ out, int nvec){
  int i = blockIdx.x*blockDim.x + threadIdx.x;
  if (i >= nvec) return;
  float4 v = *((const float4*)in + i);
  *((ushort4*)out + i) = make_ushort4(f2bf(v.x), f2bf(v.y), f2bf(v.z), f2bf(v.w));
}

// ---------------- parallel folds: wave per output ----------------
__global__ __launch_bounds__(256) void fold_ws_kernel(const float* __restrict__ gat_W,
    const float* __restrict__ att_src, const float* __restrict__ att_dst,
    float* __restrict__ ws_att, int L){
  int wave = threadIdx.x >> 6, lane = threadIdx.x & 63;
  int idx = blockIdx.x*4 + wave;
  if (idx >= L*DD*8) return;
  int j = idx & 7; int k = (idx >> 3) & 127; int l = idx >> 10;
  int h = j & 3;
  const float* att = (j < 4) ? att_src : att_dst;
  const float* av = att + (size_t)(l*NHEAD + h)*DD;
  const float* Wl = gat_W + (size_t)l*DD*HDIM + (size_t)k*HDIM + h*DD;
  float acc = Wl[lane]*av[lane] + Wl[lane + 64]*av[lane + 64];
  acc = waveReduceSum(acc);
  if (lane == 0) ws_att[idx] = acc;
}

__global__ __launch_bounds__(256) void fold_we_kernel(const float* __restrict__ gat_We,
    const float* __restrict__ att_edge, float* __restrict__ we_att, int L){
  int wave = threadIdx.x >> 6, lane = threadIdx.x & 63;
  int idx = blockIdx.x*4 + wave;
  if (idx >= L*EFEAT*NHEAD) return;
  int h = idx & 3; int f = (idx >> 2) & 31; int l = idx >> 7;
  const float* av = att_edge + (size_t)(l*NHEAD + h)*DD;
  const float* Wel = gat_We + (size_t)l*EFEAT*HDIM + (size_t)f*HDIM + h*DD;
  float acc = Wel[lane]*av[lane] + Wel[lane + 64]*av[lane + 64];
  acc = waveReduceSum(acc);
  if (lane == 0) we_att[idx] = acc;
}

__global__ void fold_self_kernel(const float* __restrict__ we_att,
    const float* __restrict__ ea_sum, float invE, float* __restrict__ al_self, int L){
  int t = threadIdx.x;
  if (t >= L*NHEAD) return;
  int h = t & 3; int l = t >> 2;
  float acc = 0.f;
  for (int f = 0; f < EFEAT; f++) acc += ea_sum[f]*invE * we_att[(l*EFEAT + f)*NHEAD + h];
  al_self[t] = acc;
}

// ---------------- gat_W -> bf16 Bt[l][d][h*128+k], LDS-tiled transpose ----------------
__global__ __launch_bounds__(256) void bt_prep_kernel(const float* __restrict__ gat_W,
                                                      unsigned short* __restrict__ Bt, int LH){
  __shared__ float tile[32][33];
  int blk = blockIdx.x;
  int lh = blk >> 4;
  if (lh >= LH) return;
  int tl = blk & 15;
  int k0 = (tl & 3)*32, d0 = (tl >> 2)*32;
  int l = lh >> 2, h = lh & 3;
  const float* in = gat_W + (size_t)l*DD*HDIM + h*DD;
  unsigned short* outp = Bt + (size_t)l*DD*HDIM + h*DD;
  int tx = threadIdx.x & 31, ty = threadIdx.x >> 5;
  #pragma unroll
  for (int i = 0; i < 4; i++){
    int k = k0 + ty + i*8;
    tile[ty + i*8][tx] = in[(size_t)k*HDIM + d0 + tx];
  }
  __syncthreads();
  #pragma unroll
  for (int i = 0; i < 4; i++){
    int d = d0 + ty + i*8;
    outp[(size_t)d*HDIM + k0 + tx] = f2bf(tile[tx][ty + i*8]);
  }
}

// ---------------- merged small weight preps: embW^T, [W1a|W1b]^T, W1c frag ------
__global__ void wprep_kernel(const float* __restrict__ embW, const float* __restrict__ hW1,
                             unsigned short* __restrict__ Wte, unsigned short* __restrict__ Bhd,
                             unsigned short* __restrict__ Bh){
  int i = blockIdx.x*blockDim.x + threadIdx.x;
  if (i < DD*DD){
    int n = i >> 7, k = i & 127;
    Wte[i] = f2bf(embW[(size_t)k*DD + n]);
  } else if (i < DD*DD + 256*DD){
    int j = i - DD*DD;
    int n = j >> 7, k = j & 127;
    float v = (n < 128) ? hW1[(size_t)k*DD + n] : hW1[(size_t)(128 + k)*DD + (n - 128)];
    Bhd[j] = f2bf(v);
  } else if (i < DD*DD + 256*DD + 8*64*8){
    int j = i - DD*DD - 256*DD;
    int jj = j & 7, lane = (j >> 3) & 63, c = j >> 9;
    int k = (lane >> 4)*8 + jj, n = c*16 + (lane & 15);
    Bh[j] = f2bf(hW1[(size_t)2*DD*DD + (size_t)k*DD + n]);
  }
}

// ---------------- all fragment-linear repacks in ONE launch ----------------
// Bfl[((ks*NC + c)*64 + lane)*8 + j] = Bmat[c*16 + (lane&15)][ks*32 + (lane>>4)*8 + j]
__global__ void repack_all_kernel(const unsigned short* __restrict__ Bt,
                                  const unsigned short* __restrict__ Wte,
                                  const unsigned short* __restrict__ Bhd,
                                  unsigned short* __restrict__ Btf,
                                  unsigned short* __restrict__ Wtef,
                                  unsigned short* __restrict__ Bhdf, int L){
  int idx = blockIdx.x*blockDim.x + threadIdx.x;
  constexpr int PER = DD*HDIM/8;   // 8192 uint4 per layer
  int nBt = L*PER;
  const unsigned short* src; unsigned short* dst; int i, KD_, NC_;
  if (idx < nBt){
    int l = idx / PER; i = idx - l*PER;
    src = Bt + (size_t)l*DD*HDIM; dst = Btf + (size_t)l*DD*HDIM; KD_ = HDIM; NC_ = 8;
  } else if (idx < nBt + DD*DD/8){
    i = idx - nBt; src = Wte; dst = Wtef; KD_ = DD; NC_ = 8;
  } else if (idx < nBt + DD*DD/8 + 256*DD/8){
    i = idx - nBt - DD*DD/8; src = Bhd; dst = Bhdf; KD_ = DD; NC_ = 16;
  } else return;
  int lane = i & 63, rest = i >> 6;
  int c = rest % NC_, ks = rest / NC_;
  int row = c*16 + (lane & 15);
  int k0  = ks*32 + (lane >> 4)*8;
  *(uint4*)(dst + (size_t)i*8) = *(const uint4*)(src + (size_t)row*KD_ + k0);
}

// ---------------- unified MFMA GEMM + fused epilogues ----------------
// 2-way K-split: wave = 16 rows x half-K, coalesced fragment-linear B loads,
// one barrier + LDS acc-reduce, epilogue on the kh==0 waves. Grid = N/32
// (2x the waves of R4 -> ~3 waves/SIMD to hide L2 load latency).
template<int KD, int NOUT>
__global__ __launch_bounds__(256, 3) void gemm_fused_kernel(
    const unsigned short* __restrict__ A, const unsigned short* __restrict__ Bfl,
    const float* __restrict__ bias, float scale, int relu, int mode,
    const float* __restrict__ ln_scale, const float* __restrict__ ln_bias,
    const float* __restrict__ gamma, const float* __restrict__ beta,
    const float* __restrict__ ws_att,
    unsigned short* __restrict__ hm_bf, float* __restrict__ al_s,
    float* __restrict__ al_d, unsigned short* __restrict__ outbf, int N){
  constexpr int NC = NOUT/16;
  constexpr int NKS = KD/64;            // ks steps per K-half
  __shared__ float s_att[8*DD];
  __shared__ float sP[4][DD];
  __shared__ f32x4 sacc[2][NC][64];
  int t = threadIdx.x;
  if (mode == 0){
    for (int i = t; i < DD*8; i += 256){
      int col = i & 127, j = i >> 7;
      s_att[j*DD + col] = ws_att[col*8 + j];
    }
    for (int i = t; i < DD; i += 256){
      sP[0][i] = ln_scale[i]; sP[1][i] = ln_bias[i];
      sP[2][i] = gamma[i];    sP[3][i] = beta[i];
    }
    __syncthreads();
  }
  int wave = t >> 6, lane = t & 63;
  int rg = wave >> 1, kh = wave & 1;
  int ln15 = lane & 15, quad = lane >> 4;
  int row0 = (blockIdx.x*2 + rg)*16;
  int arow = row0 + ln15;
  if (arow > N - 1) arow = N - 1;
  const unsigned short* aptr = A + (size_t)arow*KD + kh*(KD/2) + quad*8;
  const unsigned short* bptr = Bfl + (size_t)kh*(NKS*NC)*512 + (size_t)lane*8;

  f32x4 acc[NC];
  #pragma unroll
  for (int c = 0; c < NC; c++) acc[c] = (f32x4)(0.f);

  #pragma unroll
  for (int ks = 0; ks < NKS; ks++){
    s16x8 af = *(const s16x8*)(aptr + ks*32);
    #pragma unroll
    for (int c = 0; c < NC; c++){
      s16x8 b = *(const s16x8*)(bptr + (size_t)(ks*NC + c)*512);
      acc[c] = __builtin_amdgcn_mfma_f32_16x16x32_bf16(af, b, acc[c], 0, 0, 0);
    }
  }

  if (kh){
    #pragma unroll
    for (int c = 0; c < NC; c++) sacc[rg][c][lane] = acc[c];
  }
  __syncthreads();
  if (kh) return;
  #pragma unroll
  for (int c = 0; c < NC; c++) acc[c] += sacc[rg][c][lane];

  float bv[NC];
  #pragma unroll
  for (int c = 0; c < NC; c++){
    if constexpr (NOUT == 256) bv[c] = (c < 8) ? bias[c*16 + ln15] : 0.f;
    else bv[c] = bias[c*16 + ln15];
  }

  #pragma unroll
  for (int r = 0; r < 4; r++){
    int row = row0 + quad*4 + r;
    bool valid = (row < N);
    float hv[NC];
    #pragma unroll
    for (int c = 0; c < NC; c++){
      float v = scale*acc[c][r] + bv[c];
      hv[c] = relu ? fmaxf(v, 0.f) : v;
    }
    if (mode == 1){
      if (valid){
        if constexpr (NOUT == 256){
          // head layout: pbuf[row][ln15*8 + c] (first 128) / [128 + ln15*8 + c-8]
          unsigned short us[16];
          #pragma unroll
          for (int c = 0; c < 16; c++) us[c] = f2bf(hv[c]);
          uint4 va, vb;
          va.x = (unsigned)us[0] | ((unsigned)us[1] << 16);
          va.y = (unsigned)us[2] | ((unsigned)us[3] << 16);
          va.z = (unsigned)us[4] | ((unsigned)us[5] << 16);
          va.w = (unsigned)us[6] | ((unsigned)us[7] << 16);
          vb.x = (unsigned)us[8] | ((unsigned)us[9] << 16);
          vb.y = (unsigned)us[10] | ((unsigned)us[11] << 16);
          vb.z = (unsigned)us[12] | ((unsigned)us[13] << 16);
          vb.w = (unsigned)us[14] | ((unsigned)us[15] << 16);
          *(uint4*)(outbf + (size_t)row*256 + ln15*8) = va;
          *(uint4*)(outbf + (size_t)row*256 + 128 + ln15*8) = vb;
        } else {
          #pragma unroll
          for (int c = 0; c < NC; c++)
            outbf[(size_t)row*NOUT + c*16 + ln15] = f2bf(hv[c]);
        }
      }
      continue;
    }
    if constexpr (NOUT == 128){
      float sum = 0.f;
      #pragma unroll
      for (int c = 0; c < NC; c++) sum += hv[c];
      sum = quadReduceSum(sum);
      float mu = sum * (1.f/128.f);
      float vs = 0.f;
      #pragma unroll
      for (int c = 0; c < NC; c++){ float d = hv[c] - mu; vs += d*d; }
      vs = quadReduceSum(vs);
      float rstd = rsqrtf(vs*(1.f/128.f) + 1e-5f);
      float m[NC];
      #pragma unroll
      for (int c = 0; c < NC; c++){
        int col = c*16 + ln15;
        float hn = (hv[c] - mu)*rstd*sP[0][col] + sP[1][col];
        m[c] = sP[2][col]*hn + sP[3][col];
        if (valid) hm_bf[(size_t)row*DD + col] = f2bf(m[c]);
      }
      float alv[8];
      #pragma unroll
      for (int j = 0; j < 8; j++){
        float a = 0.f;
        #pragma unroll
        for (int c = 0; c < NC; c++) a += m[c]*s_att[j*DD + c*16 + ln15];
        alv[j] = quadReduceSum(a);
      }
      if (ln15 == 0 && valid){
        *(float4*)&al_s[(size_t)row*4] = make_float4(alv[0], alv[1], alv[2], alv[3]);
        *(float4*)&al_d[(size_t)row*4] = make_float4(alv[4], alv[5], alv[6], alv[7]);
      }
    }
  }
}

// ---------------- fused softmax + weighted aggregation (block per node) --------
__global__ __launch_bounds__(64) void aggregate4_kernel(
    const unsigned short* __restrict__ hm_bf, const float* __restrict__ ale,
    const float* __restrict__ al_s, const float* __restrict__ al_d,
    const float* __restrict__ al_self4, const int* __restrict__ offs,
    const int* __restrict__ csrc, unsigned short* __restrict__ z, int N){
  __shared__ float sw0[64], sw1[64], sw2[64], sw3[64];
  __shared__ int ssrc[64];
  int n = blockIdx.x, t = threadIdx.x;
  int beg = offs[n], end = offs[n + 1];
  float4 aslf = *(const float4*)al_self4;
  float4 asn = *(const float4*)&al_s[(size_t)n*4];
  float4 adn = *(const float4*)&al_d[(size_t)n*4];
  float e0 = __expf(lrelu(asn.x + adn.x + aslf.x));
  float e1 = __expf(lrelu(asn.y + adn.y + aslf.y));
  float e2 = __expf(lrelu(asn.z + adn.z + aslf.z));
  float e3 = __expf(lrelu(asn.w + adn.w + aslf.w));
  ushort2 hv = *((const ushort2*)(hm_bf + (size_t)n*DD) + t);
  float h0 = bf2f(hv.x), h1 = bf2f(hv.y);
  float ac00 = e0*h0, ac01 = e0*h1;
  float ac10 = e1*h0, ac11 = e1*h1;
  float ac20 = e2*h0, ac21 = e2*h1;
  float ac30 = e3*h0, ac31 = e3*h1;
  float den0 = e0, den1 = e1, den2 = e2, den3 = e3;
  for (int c0 = beg; c0 < end; c0 += 64){
    int p = c0 + t;
    if (p < end){
      int s = csrc[p];
      float4 ae = *(const float4*)&ale[(size_t)p*4];
      float4 as = *(const float4*)&al_s[(size_t)s*4];
      sw0[t] = __expf(lrelu(as.x + adn.x + ae.x));
      sw1[t] = __expf(lrelu(as.y + adn.y + ae.y));
      sw2[t] = __expf(lrelu(as.z + adn.z + ae.z));
      sw3[t] = __expf(lrelu(as.w + adn.w + ae.w));
      ssrc[t] = s;
    }
    __syncthreads();
    int cnt = min(64, end - c0);
    int i = 0;
    for (; i + 4 <= cnt; i += 4){   // 4-deep: keep 4 scattered row-loads in flight
      int sA = ssrc[i], sB = ssrc[i + 1], sC = ssrc[i + 2], sD = ssrc[i + 3];
      ushort2 vA = *((const ushort2*)(hm_bf + (size_t)sA*DD) + t);
      ushort2 vB = *((const ushort2*)(hm_bf + (size_t)sB*DD) + t);
      ushort2 vC = *((const ushort2*)(hm_bf + (size_t)sC*DD) + t);
      ushort2 vD = *((const ushort2*)(hm_bf + (size_t)sD*DD) + t);
      float wA0 = sw0[i], wA1 = sw1[i], wA2 = sw2[i], wA3 = sw3[i];
      float wB0 = sw0[i+1], wB1 = sw1[i+1], wB2 = sw2[i+1], wB3 = sw3[i+1];
      float wC0 = sw0[i+2], wC1 = sw1[i+2], wC2 = sw2[i+2], wC3 = sw3[i+2];
      float wD0 = sw0[i+3], wD1 = sw1[i+3], wD2 = sw2[i+3], wD3 = sw3[i+3];
      float vA0 = bf2f(vA.x), vA1 = bf2f(vA.y);
      float vB0 = bf2f(vB.x), vB1 = bf2f(vB.y);
      float vC0 = bf2f(vC.x), vC1 = bf2f(vC.y);
      float vD0 = bf2f(vD.x), vD1 = bf2f(vD.y);
      ac00 += wA0*vA0 + wB0*vB0 + wC0*vC0 + wD0*vD0;
      ac01 += wA0*vA1 + wB0*vB1 + wC0*vC1 + wD0*vD1;
      ac10 += wA1*vA0 + wB1*vB0 + wC1*vC0 + wD1*vD0;
      ac11 += wA1*vA1 + wB1*vB1 + wC1*vC1 + wD1*vD1;
      ac20 += wA2*vA0 + wB2*vB0 + wC2*vC0 + wD2*vD0;
      ac21 += wA2*vA1 + wB2*vB1 + wC2*vC1 + wD2*vD1;
      ac30 += wA3*vA0 + wB3*vB0 + wC3*vC0 + wD3*vD0;
      ac31 += wA3*vA1 + wB3*vB1 + wC3*vC1 + wD3*vD1;
      den0 += wA0 + wB0 + wC0 + wD0; den1 += wA1 + wB1 + wC1 + wD1;
      den2 += wA2 + wB2 + wC2 + wD2; den3 += wA3 + wB3 + wC3 + wD3;
    }
    for (; i < cnt; i++){
      int s = ssrc[i];
      float w0 = sw0[i], w1 = sw1[i], w2 = sw2[i], w3 = sw3[i];
      ushort2 v2 = *((const ushort2*)(hm_bf + (size_t)s*DD) + t);
      float v0 = bf2f(v2.x), v1 = bf2f(v2.y);
      ac00 += w0*v0; ac01 += w0*v1;
      ac10 += w1*v0; ac11 += w1*v1;
      ac20 += w2*v0; ac21 += w2*v1;
      ac30 += w3*v0; ac31 += w3*v1;
      den0 += w0; den1 += w1; den2 += w2; den3 += w3;
    }
    __syncthreads();
  }
  float r0 = 1.f/(den0 + 1e-16f), r1 = 1.f/(den1 + 1e-16f);
  float r2 = 1.f/(den2 + 1e-16f), r3 = 1.f/(den3 + 1e-16f);
  size_t zb = (size_t)n*HDIM;
  ushort2* zp = (ushort2*)(z + zb);
  zp[0*64 + t] = make_ushort2(f2bf(ac00*r0), f2bf(ac01*r0));
  zp[1*64 + t] = make_ushort2(f2bf(ac10*r1), f2bf(ac11*r1));
  zp[2*64 + t] = make_ushort2(f2bf(ac20*r2), f2bf(ac21*r2));
  zp[3*64 + t] = make_ushort2(f2bf(ac30*r3), f2bf(ac31*r3));
}

// ---------------- MFMA edge head: out[e] = relu(p[s]+p[d]+ea@W1c)@W2 + b2 ------------
__global__ __launch_bounds__(256) void head_mfma_kernel(
    const unsigned short* __restrict__ eap, const int* __restrict__ posOf,
    const unsigned short* __restrict__ Bh, const unsigned short* __restrict__ pbuf,
    const float* __restrict__ W2, const float* __restrict__ b2,
    const int* __restrict__ srcA, const int* __restrict__ dstA,
    float* __restrict__ out, int E){
  int t = threadIdx.x;
  int wave = t >> 6, lane = t & 63;
  int ln15 = lane & 15, quad = lane >> 4;
  int e0 = (blockIdx.x*4 + wave)*16;
  if (e0 >= E) return;
  int arow = e0 + ln15;
  if (arow > E - 1) arow = E - 1;
  int ap = posOf[arow];
  s16x8 a = *(const s16x8*)(eap + (size_t)ap*EFEAT + quad*8);
  f32x4 acc[8];
  #pragma unroll
  for (int c = 0; c < 8; c++){
    s16x8 b = *(const s16x8*)(Bh + ((size_t)c*64 + lane)*8);
    acc[c] = __builtin_amdgcn_mfma_f32_16x16x32_bf16(a, b, (f32x4)(0.f), 0, 0, 0);
  }
  float w2v[8];
  #pragma unroll
  for (int c = 0; c < 8; c++) w2v[c] = W2[c*16 + ln15];
  float res[4];
  #pragma unroll
  for (int r = 0; r < 4; r++){
    int e = e0 + quad*4 + r;
    int ec = (e < E) ? e : E - 1;
    int s = srcA[ec], d = dstA[ec];
    s16x8 pa = *(const s16x8*)(pbuf + (size_t)s*256 + ln15*8);
    s16x8 pb = *(const s16x8*)(pbuf + (size_t)d*256 + 128 + ln15*8);
    float sum = 0.f;
    #pragma unroll
    for (int c = 0; c < 8; c++){
      float q = acc[c][r] + bf2f((unsigned short)pa[c]) + bf2f((unsigned short)pb[c]);
      sum += fmaxf(q, 0.f) * w2v[c];
    }
    res[r] = sum;
  }
  #pragma unroll
  for (int r = 0; r < 4; r++){
    float v = res[r];
    v += __shfl_xor(v, 1, 64); v += __shfl_xor(v, 2, 64);
    v += __shfl_xor(v, 4, 64); v += __shfl_xor(v, 8, 64);
    res[r] = v;
  }
  if (ln15 == 0){
    float bb = b2[0];
    #pragma unroll
    for (int r = 0; r < 4; r++){
      int e = e0 + quad*4 + r;
      if (e < E) out[e] = res[r] + bb;
    }
  }
}

extern "C" void kernel_launch(void* const* d_in, const int* in_sizes, int n_in,
                              void* d_out, int out_size, void* d_ws, size_t ws_size,
                              hipStream_t stream){
  const float* x      = (const float*)d_in[0];
  const int*   eidx   = (const int*)d_in[1];
  const float* eattr  = (const float*)d_in[2];
  const float* gamma  = (const float*)d_in[3];
  const float* beta   = (const float*)d_in[4];
  const float* embW   = (const float*)d_in[5];
  const float* embB   = (const float*)d_in[6];
  const float* lnS    = (const float*)d_in[7];
  const float* lnB    = (const float*)d_in[8];
  const float* gatW   = (const float*)d_in[9];
  const float* attS   = (const float*)d_in[10];
  const float* attD   = (const float*)d_in[11];
  const float* gatWe  = (const float*)d_in[12];
  const float* attE   = (const float*)d_in[13];
  const float* gatB   = (const float*)d_in[14];
  const float* hW1    = (const float*)d_in[15];
  const float* hB1    = (const float*)d_in[16];
  const float* hW2    = (const float*)d_in[17];
  const float* hB2    = (const float*)d_in[18];
  float* out = (float*)d_out;

  int N = in_sizes[0] / DD;
  int E = in_sizes[1] / 2;
  int L = in_sizes[3] / DD;
  int Npad = (N + 63) & ~63;

  const int* srcA = eidx;
  const int* dstA = eidx + E;

  float* ws = (float*)d_ws;
  float* ea_sum  = ws + 0;
  float* we_att  = ws + 64;
  float* al_self = ws + 1024;
  float* ws_att  = ws + 2048;
  size_t o = 8192;
  int* deg    = (int*)(ws + o); o += N;
  int* offs   = (int*)(ws + o); o += N + 1;
  int* cursor = (int*)(ws + o); o += N;
  int* csrc   = (int*)(ws + o); o += E;
  int* posOf  = (int*)(ws + o); o += E;
  o = (o + 255) & ~(size_t)255;
  unsigned short* Bt  = (unsigned short*)(ws + o); o += (size_t)L*DD*HDIM/2;
  unsigned short* Btf = (unsigned short*)(ws + o); o += (size_t)L*DD*HDIM/2;
  unsigned short* Bh  = (unsigned short*)(ws + o); o += 8*64*8/2;
  unsigned short* Wte = (unsigned short*)(ws + o); o += DD*DD/2;
  unsigned short* Wtef= (unsigned short*)(ws + o); o += DD*DD/2;
  unsigned short* Bhd = (unsigned short*)(ws + o); o += 256*DD/2;
  unsigned short* Bhdf= (unsigned short*)(ws + o); o += 256*DD/2;
  unsigned short* xbf = (unsigned short*)(ws + o); o += (size_t)N*DD/2;
  unsigned short* hm_bf = (unsigned short*)(ws + o); o += (size_t)N*DD/2;
  float* al_s  = ws + o; o += (size_t)N*4;
  float* al_d  = ws + o; o += (size_t)N*4;
  unsigned short* eap = (unsigned short*)(ws + o); o += (size_t)E*EFEAT/2;
  float* ale   = ws + o; o += (size_t)L*E*4;
  unsigned short* z = (unsigned short*)(ws + o); o += (size_t)Npad*HDIM/2;
  unsigned short* hbf  = hm_bf;
  unsigned short* pbuf = z;

  hipMemsetAsync(ea_sum, 0, EFEAT*sizeof(float), stream);
  hipMemsetAsync(deg, 0, (size_t)N*sizeof(int), stream);
  hist_kernel<<<(E + 255)/256, 256, 0, stream>>>(dstA, deg, E);
  scan_kernel<<<1, 1024, 0, stream>>>(deg, offs, N);
  hipMemcpyAsync(cursor, offs, (size_t)N*sizeof(int), hipMemcpyDeviceToDevice, stream);
  scatter_kernel<<<(E + 255)/256, 256, 0, stream>>>(dstA, srcA, cursor, csrc, posOf, E);
  fold_ws_kernel<<<(L*DD*8 + 3)/4, 256, 0, stream>>>(gatW, attS, attD, ws_att, L);
  fold_we_kernel<<<(L*EFEAT*NHEAD + 3)/4, 256, 0, stream>>>(gatWe, attE, we_att, L);
  bt_prep_kernel<<<L*NHEAD*16, 256, 0, stream>>>(gatW, Bt, L*NHEAD);
  wprep_kernel<<<(DD*DD + 256*DD + 8*64*8 + 255)/256, 256, 0, stream>>>(
      embW, hW1, Wte, Bhd, Bh);
  bf16_conv_kernel<<<(N*DD/4 + 255)/256, 256, 0, stream>>>(x, xbf, N*DD/4);
  edge_all_kernel<<<(E + 255)/256, 256, 0, stream>>>(eattr, posOf, we_att,
      eap, ale, ea_sum, E, L);
  fold_self_kernel<<<1, 64, 0, stream>>>(we_att, ea_sum, 1.0f/(float)E, al_self, L);
  repack_all_kernel<<<(L*DD*HDIM/8 + DD*DD/8 + 256*DD/8 + 255)/256, 256, 0, stream>>>(
      Bt, Wte, Bhd, Btf, Wtef, Bhdf, L);

  // embed + LN/FiLM/al (layer 0)
  gemm_fused_kernel<128,128><<<(N + 31)/32, 256, 0, stream>>>(
      xbf, Wtef, embB, 1.0f, 0, 0, lnS, lnB, gamma, beta, ws_att,
      hm_bf, al_s, al_d, nullptr, N);

  for (int l = 0; l < L; l++){
    aggregate4_kernel<<<N, 64, 0, stream>>>(hm_bf, ale + (size_t)l*E*4,
        al_s, al_d, al_self + (size_t)l*NHEAD, offs, csrc, z, N);
    if (l < L - 1){
      gemm_fused_kernel<512,128><<<(N + 31)/32, 256, 0, stream>>>(
          z, Btf + (size_t)l*DD*HDIM, gatB + (size_t)l*DD, 0.25f, 1, 0,
          lnS + (l+1)*DD, lnB + (l+1)*DD, gamma + (l+1)*DD, beta + (l+1)*DD,
          ws_att + (size_t)(l+1)*DD*8, hm_bf, al_s, al_d, nullptr, N);
    } else {
      gemm_fused_kernel<512,128><<<(N + 31)/32, 256, 0, stream>>>(
          z, Btf + (size_t)l*DD*HDIM, gatB + (size_t)l*DD, 0.25f, 1, 1,
          nullptr, nullptr, nullptr, nullptr, nullptr,
          nullptr, nullptr, nullptr, hbf, N);
    }
  }

  // head pre-projection: pbuf[N,256] = hbf @ [W1a|W1b] (+hB1 on cols<128)
  gemm_fused_kernel<128,256><<<(N + 31)/32, 256, 0, stream>>>(
      hbf, Bhdf, hB1, 1.0f, 0, 1, nullptr, nullptr, nullptr, nullptr, nullptr,
      nullptr, nullptr, nullptr, pbuf, N);

  head_mfma_kernel<<<(E + 63)/64, 256, 0, stream>>>(eap, posOf, Bh, pbuf,
      hW2, hB2, srcA, dstA, out, E);
}

// Round 6
// 610.619 us; speedup vs baseline: 1.1662x; 1.0336x over previous
//
#include <hip/hip_runtime.h>

#define DD 128      // GNN_DIM == NODE_FEAT
#define HDIM 512    // H * D
#define EFEAT 32
#define NHEAD 4

typedef short s16x8 __attribute__((ext_vector_type(8)));
typedef float f32x4 __attribute__((ext_vector_type(4)));

__device__ __forceinline__ float lrelu(float x){ return x > 0.f ? x : 0.2f*x; }

__device__ __forceinline__ unsigned short f2bf(float f){
  unsigned u = __float_as_uint(f);
  unsigned r = (u + 0x7FFFu + ((u >> 16) & 1u)) >> 16;
  return (unsigned short)r;
}
__device__ __forceinline__ float bf2f(unsigned short u){
  return __uint_as_float(((unsigned)u) << 16);
}

__device__ __forceinline__ float waveReduceSum(float v){
  #pragma unroll
  for (int m = 1; m < 64; m <<= 1) v += __shfl_xor(v, m, 64);
  return v;
}
__device__ __forceinline__ float quadReduceSum(float v){
  v += __shfl_xor(v, 1, 64); v += __shfl_xor(v, 2, 64);
  v += __shfl_xor(v, 4, 64); v += __shfl_xor(v, 8, 64);
  return v;
}

// ---------------- edge-attr column sums (float4, saturating grid) ----------------
__global__ __launch_bounds__(256) void ea_sum4_kernel(const float* __restrict__ ea,
                                                      float* __restrict__ ea_sum, int E){
  __shared__ float s[EFEAT];
  int t = threadIdx.x;
  if (t < EFEAT) s[t] = 0.f;
  __syncthreads();
  int nvec = E*8;
  float4 acc = make_float4(0.f, 0.f, 0.f, 0.f);
  for (int i = blockIdx.x*256 + t; i < nvec; i += gridDim.x*256){
    float4 v = *((const float4*)ea + i);
    acc.x += v.x; acc.y += v.y; acc.z += v.z; acc.w += v.w;
  }
  int cg = (t & 7)*4;
  atomicAdd(&s[cg + 0], acc.x); atomicAdd(&s[cg + 1], acc.y);
  atomicAdd(&s[cg + 2], acc.z); atomicAdd(&s[cg + 3], acc.w);
  __syncthreads();
  if (t < EFEAT) atomicAdd(&ea_sum[t], s[t]);
}

// ---------------- CSR build over dst ----------------
__global__ void hist_kernel(const int* __restrict__ dst, int* __restrict__ deg, int E){
  int e = blockIdx.x*blockDim.x + threadIdx.x;
  if (e < E) atomicAdd(&deg[dst[e]], 1);
}

__global__ void scan_kernel(const int* __restrict__ deg, int* __restrict__ offs, int N){
  __shared__ int s[1024];
  int t = threadIdx.x;
  int chunk = (N + 1023) >> 10;
  int b = t*chunk, e = min(b + chunk, N);
  int sum = 0;
  for (int i = b; i < e; i++) sum += deg[i];
  s[t] = sum;
  __syncthreads();
  for (int d = 1; d < 1024; d <<= 1){
    int x = (t >= d) ? s[t - d] : 0;
    __syncthreads();
    s[t] += x;
    __syncthreads();
  }
  int run = s[t] - sum;
  for (int i = b; i < e; i++){ offs[i] = run; run += deg[i]; }
  if (t == 1023) offs[N] = s[1023];
}

__global__ void scatter_kernel(const int* __restrict__ dst, const int* __restrict__ src,
                               int* __restrict__ cursor, int* __restrict__ csrc,
                               int* __restrict__ posOf, int E){
  int e = blockIdx.x*blockDim.x + threadIdx.x;
  if (e < E){
    int d = dst[e];
    int p = atomicAdd(&cursor[d], 1);
    csrc[p] = src[e];
    posOf[e] = p;
  }
}

// ---------------- convert edge attrs, scatter into CSR order (bf16) ------------
__global__ void eap_prep_kernel(const float* __restrict__ ea, const int* __restrict__ posOf,
                                unsigned short* __restrict__ eap, int E){
  int idx = blockIdx.x*blockDim.x + threadIdx.x;
  int e = idx >> 3, q = idx & 7;
  if (e >= E) return;
  int p = posOf[e];
  float4 v = *((const float4*)(ea + (size_t)e*EFEAT) + q);
  ushort4 u = make_ushort4(f2bf(v.x), f2bf(v.y), f2bf(v.z), f2bf(v.w));
  *((ushort4*)(eap + (size_t)p*EFEAT) + q) = u;
}

// ---------------- per-edge attention logits for ALL layers (CSR order) ---------
// ale[l][p][4] = eap[p] @ we_att[l]  -- coalesced read of eap, coalesced write.
__global__ __launch_bounds__(256) void ale_prep_kernel(
    const unsigned short* __restrict__ eap, const float* __restrict__ we_att,
    float* __restrict__ ale, int E, int L){
  __shared__ float sea[256][33];
  __shared__ float swe[6*EFEAT*NHEAD];
  int t = threadIdx.x;
  for (int i = t; i < L*EFEAT*NHEAD; i += 256) swe[i] = we_att[i];
  size_t p0 = (size_t)blockIdx.x*256;
  int navail = min(256, E - (int)p0);
  for (int i = t; i < navail*4; i += 256){
    uint4 v = *((const uint4*)(eap + p0*EFEAT) + i);
    int el = i >> 2, q = i & 3;
    unsigned arr[4] = {v.x, v.y, v.z, v.w};
    #pragma unroll
    for (int j = 0; j < 4; j++){
      sea[el][q*8 + j*2]     = bf2f((unsigned short)(arr[j] & 0xffff));
      sea[el][q*8 + j*2 + 1] = bf2f((unsigned short)(arr[j] >> 16));
    }
  }
  __syncthreads();
  if ((int)p0 + t >= E) return;
  float ea[EFEAT];
  #pragma unroll
  for (int f = 0; f < EFEAT; f++) ea[f] = sea[t][f];
  size_t p = p0 + t;
  for (int l = 0; l < L; l++){
    float a0 = 0.f, a1 = 0.f, a2 = 0.f, a3 = 0.f;
    const float* w = &swe[l*EFEAT*NHEAD];
    #pragma unroll
    for (int f = 0; f < EFEAT; f++){
      float v = ea[f];
      a0 += v*w[f*4 + 0]; a1 += v*w[f*4 + 1];
      a2 += v*w[f*4 + 2]; a3 += v*w[f*4 + 3];
    }
    *(float4*)&ale[((size_t)l*E + p)*4] = make_float4(a0, a1, a2, a3);
  }
}

// ---------------- fp32 -> bf16 convert (float4 -> ushort4) ----------------
__global__ void bf16_conv_kernel(const float* __restrict__ in,
                                 unsigned short* __restrict__ out, int nvec){
  int i = blockIdx.x*blockDim.x + threadIdx.x;
  if (i >= nvec) return;
  float4 v = *((const float4*)in + i);
  *((ushort4*)out + i) = make_ushort4(f2bf(v.x), f2bf(v.y), f2bf(v.z), f2bf(v.w));
}

// ---------------- parallel folds: wave per output ----------------
__global__ __launch_bounds__(256) void fold_ws_kernel(const float* __restrict__ gat_W,
    const float* __restrict__ att_src, const float* __restrict__ att_dst,
    float* __restrict__ ws_att, int L){
  int wave = threadIdx.x >> 6, lane = threadIdx.x & 63;
  int idx = blockIdx.x*4 + wave;
  if (idx >= L*DD*8) return;
  int j = idx & 7; int k = (idx >> 3) & 127; int l = idx >> 10;
  int h = j & 3;
  const float* att = (j < 4) ? att_src : att_dst;
  const float* av = att + (size_t)(l*NHEAD + h)*DD;
  const float* Wl = gat_W + (size_t)l*DD*HDIM + (size_t)k*HDIM + h*DD;
  float acc = Wl[lane]*av[lane] + Wl[lane + 64]*av[lane + 64];
  acc = waveReduceSum(acc);
  if (lane == 0) ws_att[idx] = acc;
}

__global__ __launch_bounds__(256) void fold_we_kernel(const float* __restrict__ gat_We,
    const float* __restrict__ att_edge, float* __restrict__ we_att, int L){
  int wave = threadIdx.x >> 6, lane = threadIdx.x & 63;
  int idx = blockIdx.x*4 + wave;
  if (idx >= L*EFEAT*NHEAD) return;
  int h = idx & 3; int f = (idx >> 2) & 31; int l = idx >> 7;
  const float* av = att_edge + (size_t)(l*NHEAD + h)*DD;
  const float* Wel = gat_We + (size_t)l*EFEAT*HDIM + (size_t)f*HDIM + h*DD;
  float acc = Wel[lane]*av[lane] + Wel[lane + 64]*av[lane + 64];
  acc = waveReduceSum(acc);
  if (lane == 0) we_att[idx] = acc;
}

__global__ void fold_self_kernel(const float* __restrict__ we_att,
    const float* __restrict__ ea_sum, float invE, float* __restrict__ al_self, int L){
  int t = threadIdx.x;
  if (t >= L*NHEAD) return;
  int h = t & 3; int l = t >> 2;
  float acc = 0.f;
  for (int f = 0; f < EFEAT; f++) acc += ea_sum[f]*invE * we_att[(l*EFEAT + f)*NHEAD + h];
  al_self[t] = acc;
}

// ---------------- gat_W -> bf16 Bt[l][d][h*128+k], LDS-tiled transpose ----------------
__global__ __launch_bounds__(256) void bt_prep_kernel(const float* __restrict__ gat_W,
                                                      unsigned short* __restrict__ Bt, int LH){
  __shared__ float tile[32][33];
  int blk = blockIdx.x;
  int lh = blk >> 4;
  if (lh >= LH) return;
  int tl = blk & 15;
  int k0 = (tl & 3)*32, d0 = (tl >> 2)*32;
  int l = lh >> 2, h = lh & 3;
  const float* in = gat_W + (size_t)l*DD*HDIM + h*DD;
  unsigned short* outp = Bt + (size_t)l*DD*HDIM + h*DD;
  int tx = threadIdx.x & 31, ty = threadIdx.x >> 5;
  #pragma unroll
  for (int i = 0; i < 4; i++){
    int k = k0 + ty + i*8;
    tile[ty + i*8][tx] = in[(size_t)k*HDIM + d0 + tx];
  }
  __syncthreads();
  #pragma unroll
  for (int i = 0; i < 4; i++){
    int d = d0 + ty + i*8;
    outp[(size_t)d*HDIM + k0 + tx] = f2bf(tile[tx][ty + i*8]);
  }
}

// ---------------- merged small weight preps: embW^T, [W1a|W1b]^T, W1c frag ------
__global__ void wprep_kernel(const float* __restrict__ embW, const float* __restrict__ hW1,
                             unsigned short* __restrict__ Wte, unsigned short* __restrict__ Bhd,
                             unsigned short* __restrict__ Bh){
  int i = blockIdx.x*blockDim.x + threadIdx.x;
  if (i < DD*DD){
    int n = i >> 7, k = i & 127;
    Wte[i] = f2bf(embW[(size_t)k*DD + n]);
  } else if (i < DD*DD + 256*DD){
    int j = i - DD*DD;
    int n = j >> 7, k = j & 127;
    float v = (n < 128) ? hW1[(size_t)k*DD + n] : hW1[(size_t)(128 + k)*DD + (n - 128)];
    Bhd[j] = f2bf(v);
  } else if (i < DD*DD + 256*DD + 8*64*8){
    int j = i - DD*DD - 256*DD;
    int jj = j & 7, lane = (j >> 3) & 63, c = j >> 9;
    int k = (lane >> 4)*8 + jj, n = c*16 + (lane & 15);
    Bh[j] = f2bf(hW1[(size_t)2*DD*DD + (size_t)k*DD + n]);
  }
}

// ---------------- all fragment-linear repacks in ONE launch ----------------
// Bfl[((ks*NC + c)*64 + lane)*8 + j] = Bmat[c*16 + (lane&15)][ks*32 + (lane>>4)*8 + j]
__global__ void repack_all_kernel(const unsigned short* __restrict__ Bt,
                                  const unsigned short* __restrict__ Wte,
                                  const unsigned short* __restrict__ Bhd,
                                  unsigned short* __restrict__ Btf,
                                  unsigned short* __restrict__ Wtef,
                                  unsigned short* __restrict__ Bhdf, int L){
  int idx = blockIdx.x*blockDim.x + threadIdx.x;
  constexpr int PER = DD*HDIM/8;   // 8192 uint4 per layer
  int nBt = L*PER;
  const unsigned short* src; unsigned short* dst; int i, KD_, NC_;
  if (idx < nBt){
    int l = idx / PER; i = idx - l*PER;
    src = Bt + (size_t)l*DD*HDIM; dst = Btf + (size_t)l*DD*HDIM; KD_ = HDIM; NC_ = 8;
  } else if (idx < nBt + DD*DD/8){
    i = idx - nBt; src = Wte; dst = Wtef; KD_ = DD; NC_ = 8;
  } else if (idx < nBt + DD*DD/8 + 256*DD/8){
    i = idx - nBt - DD*DD/8; src = Bhd; dst = Bhdf; KD_ = DD; NC_ = 16;
  } else return;
  int lane = i & 63, rest = i >> 6;
  int c = rest % NC_, ks = rest / NC_;
  int row = c*16 + (lane & 15);
  int k0  = ks*32 + (lane >> 4)*8;
  *(uint4*)(dst + (size_t)i*8) = *(const uint4*)(src + (size_t)row*KD_ + k0);
}

// ---------------- unified MFMA GEMM + fused epilogues ----------------
// 2-way K-split: wave = 16 rows x half-K, coalesced fragment-linear B loads,
// one barrier + LDS acc-reduce, epilogue on the kh==0 waves.
template<int KD, int NOUT>
__global__ __launch_bounds__(256, 3) void gemm_fused_kernel(
    const unsigned short* __restrict__ A, const unsigned short* __restrict__ Bfl,
    const float* __restrict__ bias, float scale, int relu, int mode,
    const float* __restrict__ ln_scale, const float* __restrict__ ln_bias,
    const float* __restrict__ gamma, const float* __restrict__ beta,
    const float* __restrict__ ws_att,
    unsigned short* __restrict__ hm_bf, float* __restrict__ al_s,
    float* __restrict__ al_d, unsigned short* __restrict__ outbf, int N){
  constexpr int NC = NOUT/16;
  constexpr int NKS = KD/64;            // ks steps per K-half
  __shared__ float s_att[8*DD];
  __shared__ float sP[4][DD];
  __shared__ f32x4 sacc[2][NC][64];
  int t = threadIdx.x;
  if (mode == 0){
    for (int i = t; i < DD*8; i += 256){
      int col = i & 127, j = i >> 7;
      s_att[j*DD + col] = ws_att[col*8 + j];
    }
    for (int i = t; i < DD; i += 256){
      sP[0][i] = ln_scale[i]; sP[1][i] = ln_bias[i];
      sP[2][i] = gamma[i];    sP[3][i] = beta[i];
    }
    __syncthreads();
  }
  int wave = t >> 6, lane = t & 63;
  int rg = wave >> 1, kh = wave & 1;
  int ln15 = lane & 15, quad = lane >> 4;
  int row0 = (blockIdx.x*2 + rg)*16;
  int arow = row0 + ln15;
  if (arow > N - 1) arow = N - 1;
  const unsigned short* aptr = A + (size_t)arow*KD + kh*(KD/2) + quad*8;
  const unsigned short* bptr = Bfl + (size_t)kh*(NKS*NC)*512 + (size_t)lane*8;

  f32x4 acc[NC];
  #pragma unroll
  for (int c = 0; c < NC; c++) acc[c] = (f32x4)(0.f);

  #pragma unroll
  for (int ks = 0; ks < NKS; ks++){
    s16x8 af = *(const s16x8*)(aptr + ks*32);
    #pragma unroll
    for (int c = 0; c < NC; c++){
      s16x8 b = *(const s16x8*)(bptr + (size_t)(ks*NC + c)*512);
      acc[c] = __builtin_amdgcn_mfma_f32_16x16x32_bf16(af, b, acc[c], 0, 0, 0);
    }
  }

  if (kh){
    #pragma unroll
    for (int c = 0; c < NC; c++) sacc[rg][c][lane] = acc[c];
  }
  __syncthreads();
  if (kh) return;
  #pragma unroll
  for (int c = 0; c < NC; c++) acc[c] += sacc[rg][c][lane];

  float bv[NC];
  #pragma unroll
  for (int c = 0; c < NC; c++){
    if constexpr (NOUT == 256) bv[c] = (c < 8) ? bias[c*16 + ln15] : 0.f;
    else bv[c] = bias[c*16 + ln15];
  }

  #pragma unroll
  for (int r = 0; r < 4; r++){
    int row = row0 + quad*4 + r;
    bool valid = (row < N);
    float hv[NC];
    #pragma unroll
    for (int c = 0; c < NC; c++){
      float v = scale*acc[c][r] + bv[c];
      hv[c] = relu ? fmaxf(v, 0.f) : v;
    }
    if (mode == 1){
      if (valid){
        if constexpr (NOUT == 256){
          // head layout: pbuf[row][ln15*8 + c] (first 128) / [128 + ln15*8 + c-8]
          unsigned short us[16];
          #pragma unroll
          for (int c = 0; c < 16; c++) us[c] = f2bf(hv[c]);
          uint4 va, vb;
          va.x = (unsigned)us[0] | ((unsigned)us[1] << 16);
          va.y = (unsigned)us[2] | ((unsigned)us[3] << 16);
          va.z = (unsigned)us[4] | ((unsigned)us[5] << 16);
          va.w = (unsigned)us[6] | ((unsigned)us[7] << 16);
          vb.x = (unsigned)us[8] | ((unsigned)us[9] << 16);
          vb.y = (unsigned)us[10] | ((unsigned)us[11] << 16);
          vb.z = (unsigned)us[12] | ((unsigned)us[13] << 16);
          vb.w = (unsigned)us[14] | ((unsigned)us[15] << 16);
          *(uint4*)(outbf + (size_t)row*256 + ln15*8) = va;
          *(uint4*)(outbf + (size_t)row*256 + 128 + ln15*8) = vb;
        } else {
          #pragma unroll
          for (int c = 0; c < NC; c++)
            outbf[(size_t)row*NOUT + c*16 + ln15] = f2bf(hv[c]);
        }
      }
      continue;
    }
    if constexpr (NOUT == 128){
      float sum = 0.f;
      #pragma unroll
      for (int c = 0; c < NC; c++) sum += hv[c];
      sum = quadReduceSum(sum);
      float mu = sum * (1.f/128.f);
      float vs = 0.f;
      #pragma unroll
      for (int c = 0; c < NC; c++){ float d = hv[c] - mu; vs += d*d; }
      vs = quadReduceSum(vs);
      float rstd = rsqrtf(vs*(1.f/128.f) + 1e-5f);
      float m[NC];
      #pragma unroll
      for (int c = 0; c < NC; c++){
        int col = c*16 + ln15;
        float hn = (hv[c] - mu)*rstd*sP[0][col] + sP[1][col];
        m[c] = sP[2][col]*hn + sP[3][col];
        if (valid) hm_bf[(size_t)row*DD + col] = f2bf(m[c]);
      }
      float alv[8];
      #pragma unroll
      for (int j = 0; j < 8; j++){
        float a = 0.f;
        #pragma unroll
        for (int c = 0; c < NC; c++) a += m[c]*s_att[j*DD + c*16 + ln15];
        alv[j] = quadReduceSum(a);
      }
      if (ln15 == 0 && valid){
        *(float4*)&al_s[(size_t)row*4] = make_float4(alv[0], alv[1], alv[2], alv[3]);
        *(float4*)&al_d[(size_t)row*4] = make_float4(alv[4], alv[5], alv[6], alv[7]);
      }
    }
  }
}

// ---------------- fused softmax + weighted aggregation (block per node) --------
__global__ __launch_bounds__(64) void aggregate4_kernel(
    const unsigned short* __restrict__ hm_bf, const float* __restrict__ ale,
    const float* __restrict__ al_s, const float* __restrict__ al_d,
    const float* __restrict__ al_self4, const int* __restrict__ offs,
    const int* __restrict__ csrc, unsigned short* __restrict__ z, int N){
  __shared__ float sw0[64], sw1[64], sw2[64], sw3[64];
  __shared__ int ssrc[64];
  int n = blockIdx.x, t = threadIdx.x;
  int beg = offs[n], end = offs[n + 1];
  float4 aslf = *(const float4*)al_self4;
  float4 asn = *(const float4*)&al_s[(size_t)n*4];
  float4 adn = *(const float4*)&al_d[(size_t)n*4];
  float e0 = __expf(lrelu(asn.x + adn.x + aslf.x));
  float e1 = __expf(lrelu(asn.y + adn.y + aslf.y));
  float e2 = __expf(lrelu(asn.z + adn.z + aslf.z));
  float e3 = __expf(lrelu(asn.w + adn.w + aslf.w));
  ushort2 hv = *((const ushort2*)(hm_bf + (size_t)n*DD) + t);
  float h0 = bf2f(hv.x), h1 = bf2f(hv.y);
  float ac00 = e0*h0, ac01 = e0*h1;
  float ac10 = e1*h0, ac11 = e1*h1;
  float ac20 = e2*h0, ac21 = e2*h1;
  float ac30 = e3*h0, ac31 = e3*h1;
  float den0 = e0, den1 = e1, den2 = e2, den3 = e3;
  for (int c0 = beg; c0 < end; c0 += 64){
    int p = c0 + t;
    if (p < end){
      int s = csrc[p];
      float4 ae = *(const float4*)&ale[(size_t)p*4];
      float4 as = *(const float4*)&al_s[(size_t)s*4];
      sw0[t] = __expf(lrelu(as.x + adn.x + ae.x));
      sw1[t] = __expf(lrelu(as.y + adn.y + ae.y));
      sw2[t] = __expf(lrelu(as.z + adn.z + ae.z));
      sw3[t] = __expf(lrelu(as.w + adn.w + ae.w));
      ssrc[t] = s;
    }
    __syncthreads();
    int cnt = min(64, end - c0);
    int i = 0;
    for (; i + 4 <= cnt; i += 4){   // 4-deep: keep 4 scattered row-loads in flight
      int sA = ssrc[i], sB = ssrc[i + 1], sC = ssrc[i + 2], sD = ssrc[i + 3];
      ushort2 vA = *((const ushort2*)(hm_bf + (size_t)sA*DD) + t);
      ushort2 vB = *((const ushort2*)(hm_bf + (size_t)sB*DD) + t);
      ushort2 vC = *((const ushort2*)(hm_bf + (size_t)sC*DD) + t);
      ushort2 vD = *((const ushort2*)(hm_bf + (size_t)sD*DD) + t);
      float wA0 = sw0[i], wA1 = sw1[i], wA2 = sw2[i], wA3 = sw3[i];
      float wB0 = sw0[i+1], wB1 = sw1[i+1], wB2 = sw2[i+1], wB3 = sw3[i+1];
      float wC0 = sw0[i+2], wC1 = sw1[i+2], wC2 = sw2[i+2], wC3 = sw3[i+2];
      float wD0 = sw0[i+3], wD1 = sw1[i+3], wD2 = sw2[i+3], wD3 = sw3[i+3];
      float vA0 = bf2f(vA.x), vA1 = bf2f(vA.y);
      float vB0 = bf2f(vB.x), vB1 = bf2f(vB.y);
      float vC0 = bf2f(vC.x), vC1 = bf2f(vC.y);
      float vD0 = bf2f(vD.x), vD1 = bf2f(vD.y);
      ac00 += wA0*vA0 + wB0*vB0 + wC0*vC0 + wD0*vD0;
      ac01 += wA0*vA1 + wB0*vB1 + wC0*vC1 + wD0*vD1;
      ac10 += wA1*vA0 + wB1*vB0 + wC1*vC0 + wD1*vD0;
      ac11 += wA1*vA1 + wB1*vB1 + wC1*vC1 + wD1*vD1;
      ac20 += wA2*vA0 + wB2*vB0 + wC2*vC0 + wD2*vD0;
      ac21 += wA2*vA1 + wB2*vB1 + wC2*vC1 + wD2*vD1;
      ac30 += wA3*vA0 + wB3*vB0 + wC3*vC0 + wD3*vD0;
      ac31 += wA3*vA1 + wB3*vB1 + wC3*vC1 + wD3*vD1;
      den0 += wA0 + wB0 + wC0 + wD0; den1 += wA1 + wB1 + wC1 + wD1;
      den2 += wA2 + wB2 + wC2 + wD2; den3 += wA3 + wB3 + wC3 + wD3;
    }
    for (; i < cnt; i++){
      int s = ssrc[i];
      float w0 = sw0[i], w1 = sw1[i], w2 = sw2[i], w3 = sw3[i];
      ushort2 v2 = *((const ushort2*)(hm_bf + (size_t)s*DD) + t);
      float v0 = bf2f(v2.x), v1 = bf2f(v2.y);
      ac00 += w0*v0; ac01 += w0*v1;
      ac10 += w1*v0; ac11 += w1*v1;
      ac20 += w2*v0; ac21 += w2*v1;
      ac30 += w3*v0; ac31 += w3*v1;
      den0 += w0; den1 += w1; den2 += w2; den3 += w3;
    }
    __syncthreads();
  }
  float r0 = 1.f/(den0 + 1e-16f), r1 = 1.f/(den1 + 1e-16f);
  float r2 = 1.f/(den2 + 1e-16f), r3 = 1.f/(den3 + 1e-16f);
  size_t zb = (size_t)n*HDIM;
  ushort2* zp = (ushort2*)(z + zb);
  zp[0*64 + t] = make_ushort2(f2bf(ac00*r0), f2bf(ac01*r0));
  zp[1*64 + t] = make_ushort2(f2bf(ac10*r1), f2bf(ac11*r1));
  zp[2*64 + t] = make_ushort2(f2bf(ac20*r2), f2bf(ac21*r2));
  zp[3*64 + t] = make_ushort2(f2bf(ac30*r3), f2bf(ac31*r3));
}

// ---------------- MFMA edge head: out[e] = relu(p[s]+p[d]+ea@W1c)@W2 + b2 ------------
__global__ __launch_bounds__(256) void head_mfma_kernel(
    const unsigned short* __restrict__ eap, const int* __restrict__ posOf,
    const unsigned short* __restrict__ Bh, const unsigned short* __restrict__ pbuf,
    const float* __restrict__ W2, const float* __restrict__ b2,
    const int* __restrict__ srcA, const int* __restrict__ dstA,
    float* __restrict__ out, int E){
  int t = threadIdx.x;
  int wave = t >> 6, lane = t & 63;
  int ln15 = lane & 15, quad = lane >> 4;
  int e0 = (blockIdx.x*4 + wave)*16;
  if (e0 >= E) return;
  int arow = e0 + ln15;
  if (arow > E - 1) arow = E - 1;
  int ap = posOf[arow];
  s16x8 a = *(const s16x8*)(eap + (size_t)ap*EFEAT + quad*8);
  f32x4 acc[8];
  #pragma unroll
  for (int c = 0; c < 8; c++){
    s16x8 b = *(const s16x8*)(Bh + ((size_t)c*64 + lane)*8);
    acc[c] = __builtin_amdgcn_mfma_f32_16x16x32_bf16(a, b, (f32x4)(0.f), 0, 0, 0);
  }
  float w2v[8];
  #pragma unroll
  for (int c = 0; c < 8; c++) w2v[c] = W2[c*16 + ln15];
  float res[4];
  #pragma unroll
  for (int r = 0; r < 4; r++){
    int e = e0 + quad*4 + r;
    int ec = (e < E) ? e : E - 1;
    int s = srcA[ec], d = dstA[ec];
    s16x8 pa = *(const s16x8*)(pbuf + (size_t)s*256 + ln15*8);
    s16x8 pb = *(const s16x8*)(pbuf + (size_t)d*256 + 128 + ln15*8);
    float sum = 0.f;
    #pragma unroll
    for (int c = 0; c < 8; c++){
      float q = acc[c][r] + bf2f((unsigned short)pa[c]) + bf2f((unsigned short)pb[c]);
      sum += fmaxf(q, 0.f) * w2v[c];
    }
    res[r] = sum;
  }
  #pragma unroll
  for (int r = 0; r < 4; r++){
    float v = res[r];
    v += __shfl_xor(v, 1, 64); v += __shfl_xor(v, 2, 64);
    v += __shfl_xor(v, 4, 64); v += __shfl_xor(v, 8, 64);
    res[r] = v;
  }
  if (ln15 == 0){
    float bb = b2[0];
    #pragma unroll
    for (int r = 0; r < 4; r++){
      int e = e0 + quad*4 + r;
      if (e < E) out[e] = res[r] + bb;
    }
  }
}

extern "C" void kernel_launch(void* const* d_in, const int* in_sizes, int n_in,
                              void* d_out, int out_size, void* d_ws, size_t ws_size,
                              hipStream_t stream){
  const float* x      = (const float*)d_in[0];
  const int*   eidx   = (const int*)d_in[1];
  const float* eattr  = (const float*)d_in[2];
  const float* gamma  = (const float*)d_in[3];
  const float* beta   = (const float*)d_in[4];
  const float* embW   = (const float*)d_in[5];
  const float* embB   = (const float*)d_in[6];
  const float* lnS    = (const float*)d_in[7];
  const float* lnB    = (const float*)d_in[8];
  const float* gatW   = (const float*)d_in[9];
  const float* attS   = (const float*)d_in[10];
  const float* attD   = (const float*)d_in[11];
  const float* gatWe  = (const float*)d_in[12];
  const float* attE   = (const float*)d_in[13];
  const float* gatB   = (const float*)d_in[14];
  const float* hW1    = (const float*)d_in[15];
  const float* hB1    = (const float*)d_in[16];
  const float* hW2    = (const float*)d_in[17];
  const float* hB2    = (const float*)d_in[18];
  float* out = (float*)d_out;

  int N = in_sizes[0] / DD;
  int E = in_sizes[1] / 2;
  int L = in_sizes[3] / DD;
  int Npad = (N + 63) & ~63;

  const int* srcA = eidx;
  const int* dstA = eidx + E;

  float* ws = (float*)d_ws;
  float* ea_sum  = ws + 0;
  float* we_att  = ws + 64;
  float* al_self = ws + 1024;
  float* ws_att  = ws + 2048;
  size_t o = 8192;
  int* deg    = (int*)(ws + o); o += N;
  int* offs   = (int*)(ws + o); o += N + 1;
  int* cursor = (int*)(ws + o); o += N;
  int* csrc   = (int*)(ws + o); o += E;
  int* posOf  = (int*)(ws + o); o += E;
  o = (o + 255) & ~(size_t)255;
  unsigned short* Bt  = (unsigned short*)(ws + o); o += (size_t)L*DD*HDIM/2;
  unsigned short* Btf = (unsigned short*)(ws + o); o += (size_t)L*DD*HDIM/2;
  unsigned short* Bh  = (unsigned short*)(ws + o); o += 8*64*8/2;
  unsigned short* Wte = (unsigned short*)(ws + o); o += DD*DD/2;
  unsigned short* Wtef= (unsigned short*)(ws + o); o += DD*DD/2;
  unsigned short* Bhd = (unsigned short*)(ws + o); o += 256*DD/2;
  unsigned short* Bhdf= (unsigned short*)(ws + o); o += 256*DD/2;
  unsigned short* xbf = (unsigned short*)(ws + o); o += (size_t)N*DD/2;
  unsigned short* hm_bf = (unsigned short*)(ws + o); o += (size_t)N*DD/2;
  float* al_s  = ws + o; o += (size_t)N*4;
  float* al_d  = ws + o; o += (size_t)N*4;
  unsigned short* eap = (unsigned short*)(ws + o); o += (size_t)E*EFEAT/2;
  float* ale   = ws + o; o += (size_t)L*E*4;
  unsigned short* z = (unsigned short*)(ws + o); o += (size_t)Npad*HDIM/2;
  unsigned short* hbf  = hm_bf;
  unsigned short* pbuf = z;

  hipMemsetAsync(ea_sum, 0, EFEAT*sizeof(float), stream);
  hipMemsetAsync(deg, 0, (size_t)N*sizeof(int), stream);
  ea_sum4_kernel<<<1024, 256, 0, stream>>>(eattr, ea_sum, E);
  hist_kernel<<<(E + 255)/256, 256, 0, stream>>>(dstA, deg, E);
  scan_kernel<<<1, 1024, 0, stream>>>(deg, offs, N);
  hipMemcpyAsync(cursor, offs, (size_t)N*sizeof(int), hipMemcpyDeviceToDevice, stream);
  scatter_kernel<<<(E + 255)/256, 256, 0, stream>>>(dstA, srcA, cursor, csrc, posOf, E);
  eap_prep_kernel<<<(E*8 + 255)/256, 256, 0, stream>>>(eattr, posOf, eap, E);
  fold_ws_kernel<<<(L*DD*8 + 3)/4, 256, 0, stream>>>(gatW, attS, attD, ws_att, L);
  fold_we_kernel<<<(L*EFEAT*NHEAD + 3)/4, 256, 0, stream>>>(gatWe, attE, we_att, L);
  fold_self_kernel<<<1, 64, 0, stream>>>(we_att, ea_sum, 1.0f/(float)E, al_self, L);
  bt_prep_kernel<<<L*NHEAD*16, 256, 0, stream>>>(gatW, Bt, L*NHEAD);
  wprep_kernel<<<(DD*DD + 256*DD + 8*64*8 + 255)/256, 256, 0, stream>>>(
      embW, hW1, Wte, Bhd, Bh);
  bf16_conv_kernel<<<(N*DD/4 + 255)/256, 256, 0, stream>>>(x, xbf, N*DD/4);
  ale_prep_kernel<<<(E + 255)/256, 256, 0, stream>>>(eap, we_att, ale, E, L);
  repack_all_kernel<<<(L*DD*HDIM/8 + DD*DD/8 + 256*DD/8 + 255)/256, 256, 0, stream>>>(
      Bt, Wte, Bhd, Btf, Wtef, Bhdf, L);

  // embed + LN/FiLM/al (layer 0)
  gemm_fused_kernel<128,128><<<(N + 31)/32, 256, 0, stream>>>(
      xbf, Wtef, embB, 1.0f, 0, 0, lnS, lnB, gamma, beta, ws_att,
      hm_bf, al_s, al_d, nullptr, N);

  for (int l = 0; l < L; l++){
    aggregate4_kernel<<<N, 64, 0, stream>>>(hm_bf, ale + (size_t)l*E*4,
        al_s, al_d, al_self + (size_t)l*NHEAD, offs, csrc, z, N);
    if (l < L - 1){
      gemm_fused_kernel<512,128><<<(N + 31)/32, 256, 0, stream>>>(
          z, Btf + (size_t)l*DD*HDIM, gatB + (size_t)l*DD, 0.25f, 1, 0,
          lnS + (l+1)*DD, lnB + (l+1)*DD, gamma + (l+1)*DD, beta + (l+1)*DD,
          ws_att + (size_t)(l+1)*DD*8, hm_bf, al_s, al_d, nullptr, N);
    } else {
      gemm_fused_kernel<512,128><<<(N + 31)/32, 256, 0, stream>>>(
          z, Btf + (size_t)l*DD*HDIM, gatB + (size_t)l*DD, 0.25f, 1, 1,
          nullptr, nullptr, nullptr, nullptr, nullptr,
          nullptr, nullptr, nullptr, hbf, N);
    }
  }

  // head pre-projection: pbuf[N,256] = hbf @ [W1a|W1b] (+hB1 on cols<128)
  gemm_fused_kernel<128,256><<<(N + 31)/32, 256, 0, stream>>>(
      hbf, Bhdf, hB1, 1.0f, 0, 1, nullptr, nullptr, nullptr, nullptr, nullptr,
      nullptr, nullptr, nullptr, pbuf, N);

  head_mfma_kernel<<<(E + 63)/64, 256, 0, stream>>>(eap, posOf, Bh, pbuf,
      hW2, hB2, srcA, dstA, out, E);
}